// Round 13
// baseline (170.844 us; speedup 1.0000x reference)
//
#include <hip/hip_runtime.h>
#include <hip/hip_bf16.h>

typedef unsigned short u16;
typedef unsigned int   u32;
typedef _Float16 f16x8 __attribute__((ext_vector_type(8)));
typedef float    f32x16 __attribute__((ext_vector_type(16)));

#define HEADS 16
#define D     192
#define NUP   1024

// ---- workspace layout (bytes) ----
#define XB       (2048ull*192*2)               // 786432
#define XH_OFF   0ull
#define XL_OFF   (XH_OFF + XB)
#define XT_OFF   (XL_OFF + XB)
#define WM_BYTES (64ull*192*192*2)             // 4718592
#define WTP_OFF  (XT_OFF + XB)
#define MTH_OFF  (WTP_OFF + WM_BYTES)
#define MTL_OFF  (MTH_OFF + WM_BYTES)
#define Y_BYTES  (64ull*1024*192*2)            // 25165824 (fp16)
#define Y_OFF    (MTH_OFF + 2*WM_BYTES)
#define WS_NEED  (Y_OFF + Y_BYTES)             // 41680896

__device__ __forceinline__ u16 f2h(float v) {
    _Float16 h = (_Float16)v;
    return __builtin_bit_cast(u16, h);
}
__device__ __forceinline__ float h2f(u16 v) {
    return (float)__builtin_bit_cast(_Float16, v);
}
__device__ __forceinline__ u32 pk2h(float a, float b) {      // RNE
    return (u32)f2h(a) | ((u32)f2h(b) << 16);
}
__device__ __forceinline__ u32 pk2h_rtz(float a, float b) {  // 1-instr packed
    auto r = __builtin_amdgcn_cvt_pkrtz(a, b);
    return __builtin_bit_cast(u32, r);
}

// =====================================================================
// helper: assemble B-fragment (32x32x16) from 4 packed-pair u32s in
// D-frag order (m = (r&3)+8*(r>>2)+4*(lane>>5)) via half-swap (shfl —
// HW-verified R2..R12)
// =====================================================================
__device__ __forceinline__ f16x8 make_bfrag(u32 q0, u32 q1, u32 q2, u32 q3, bool hi) {
    u32 s0 = (u32)__shfl_xor((int)q0, 32);
    u32 s1 = (u32)__shfl_xor((int)q1, 32);
    u32 s2 = (u32)__shfl_xor((int)q2, 32);
    u32 s3 = (u32)__shfl_xor((int)q3, 32);
    uint4 w;
    w.x = hi ? s2 : q0;  w.y = hi ? s3 : q1;
    w.z = hi ? q2 : s0;  w.w = hi ? q3 : s1;
    return __builtin_bit_cast(f16x8, w);
}

// =====================================================================
// Prep ALL (merged): blocks [0,768) do x->xh,xl,xT ; rest build WT/MT.
// =====================================================================
__global__ __launch_bounds__(512)
void prep_all(const float* __restrict__ x,
              const float* __restrict__ Muu, const float* __restrict__ Mdd,
              const float* __restrict__ Mud, const float* __restrict__ Mdu,
              const float* __restrict__ Auu, const float* __restrict__ Add,
              const float* __restrict__ Aud, const float* __restrict__ Adu,
              u16* __restrict__ xh, u16* __restrict__ xl, u16* __restrict__ xT,
              u16* __restrict__ wtp, u16* __restrict__ mth, u16* __restrict__ mtl)
{
    int b = blockIdx.x;
    if (b < 768) {
        int i = b*512 + threadIdx.x;           // < 2048*192
        float v = x[i];
        int n = i / D, d = i - n*D;
        u16 hi = f2h(v);
        xh[i] = hi;
        xl[i] = f2h(v - h2f(hi));
        xT[(size_t)(n >> 5)*6144 + d*32 + (n & 31)] = hi;
        return;
    }
    int idx = (b - 768)*512 + threadIdx.x;     // < 64*36864
    int th = idx / 36864, r = idx - th*36864;
    int dout = r / 192, din = r - dout*192;
    int t = th >> 4, h = th & 15;
    const float* Ap = (t==0)?Auu:(t==1)?Aud:(t==2)?Add:Adu;
    const float* Mp = (t==0)?Muu:(t==1)?Mud:(t==2)?Mdd:Mdu;
    int g = dout / 6, zc = dout - g*6, z = zc >> 1, b0 = zc & 1;
    int f = din / 6,  zb = din - f*6,  z2 = zb >> 1, b1 = zb & 1;

    float wv = 0.0f, mv = 0.0f;
    if (z2 == z) {
        const float* a = Ap + (((size_t)h*32 + g)*32 + f)*6 + z*2;
        float A0 = a[0], A1 = a[1];
        wv = (b0 == 0) ? (b1 == 0 ? A0 : -A1) : (b1 == 0 ? A1 : A0);
        const float* m = Mp + (((size_t)h*32 + f)*32 + g)*6 + z*2;
        float M0 = m[0], M1 = m[1];
        mv = (b0 == 0) ? (b1 == 0 ? M0 : -M1) : (b1 == 0 ? M1 : M0);
    }
    int ob = dout >> 5, l31 = dout & 31;
    int ks = din >> 4, kr = din & 15, g32 = kr >> 3, j = kr & 7;
    size_t pidx = ((((size_t)th*6 + ob)*12 + ks)*64 + g32*32 + l31)*8 + j;
    wtp[pidx] = f2h(wv);
    u16 mh = f2h(mv);
    mth[pidx] = mh;
    mtl[pidx] = f2h(mv - h2f(mh));
}

// =====================================================================
// Main fused kernel — 4 waves x 32 q-rows = 128 rows, 256 threads,
// grid (8,16,4) = 512 blocks = 2 blocks/CU (cross-block overlap, m114).
// LDS: single sXh + double sXT = 43520 B raw. Two barriers/iter:
// [load; SCORES(cur); SOFTMAX(prev); PV(prev); bar; store(cur+1); bar].
// Prologue: merged MFMA QM (R12-verified). 1-term fp16 scores.
// =====================================================================
__global__ __launch_bounds__(256, 2)
void attn_mfma(const u16* __restrict__ xh_g,  const u16* __restrict__ xl_g,
               const u16* __restrict__ xT_g,  const u16* __restrict__ wtp_g,
               const u16* __restrict__ mth_g, const u16* __restrict__ mtl_g,
               u16* __restrict__ y_g)
{
    const int nt = blockIdx.x, h = blockIdx.y, t = blockIdx.z;
    const int tid  = threadIdx.x;
    const int lane = tid & 63;
    const int l31  = lane & 31;
    const int g32  = lane >> 5;
    const int th   = t*16 + h;
    const int n0   = nt*128 + (tid >> 6)*32;
    const int qoff = (t <= 1) ? 0 : NUP;             // q-side rows
    const int koff = (t == 1 || t == 2) ? NUP : 0;   // k/v-side rows
    const int mtb  = koff >> 5;

    __shared__ u16 sXh[32*200];
    __shared__ u16 sXT[2][192*40];

    // ---- prologue: QM B-fragments via MFMA (3-term fp16 split) ----
    f16x8 qh[12];
    {
        f16x8 bxh[12], bxl[12];
        const u16* xrh = xh_g + (size_t)(qoff + n0 + l31)*D;
        const u16* xrl = xl_g + (size_t)(qoff + n0 + l31)*D;
        #pragma unroll
        for (int ks = 0; ks < 12; ++ks) {
            bxh[ks] = *reinterpret_cast<const f16x8*>(xrh + ks*16 + g32*8);
            bxl[ks] = *reinterpret_cast<const f16x8*>(xrl + ks*16 + g32*8);
        }
        const u16* mthb = mth_g + (size_t)th*36864;
        const u16* mtlb = mtl_g + (size_t)th*36864;
        #pragma unroll
        for (int obp = 0; obp < 3; ++obp) {      // 2 obs in flight for ILP
            const int ob0 = obp*2, ob1 = obp*2 + 1;
            f32x16 a0, a1;
            #pragma unroll
            for (int i = 0; i < 16; ++i) { a0[i] = 0.0f; a1[i] = 0.0f; }
            #pragma unroll
            for (int ks = 0; ks < 12; ++ks) {
                size_t fo0 = (((size_t)ob0*12 + ks)*64 + lane)*8;
                size_t fo1 = (((size_t)ob1*12 + ks)*64 + lane)*8;
                f16x8 amh0 = *reinterpret_cast<const f16x8*>(mthb + fo0);
                f16x8 aml0 = *reinterpret_cast<const f16x8*>(mtlb + fo0);
                f16x8 amh1 = *reinterpret_cast<const f16x8*>(mthb + fo1);
                f16x8 aml1 = *reinterpret_cast<const f16x8*>(mtlb + fo1);
                a0 = __builtin_amdgcn_mfma_f32_32x32x16_f16(amh0, bxh[ks], a0, 0, 0, 0);
                a1 = __builtin_amdgcn_mfma_f32_32x32x16_f16(amh1, bxh[ks], a1, 0, 0, 0);
                a0 = __builtin_amdgcn_mfma_f32_32x32x16_f16(amh0, bxl[ks], a0, 0, 0, 0);
                a1 = __builtin_amdgcn_mfma_f32_32x32x16_f16(amh1, bxl[ks], a1, 0, 0, 0);
                a0 = __builtin_amdgcn_mfma_f32_32x32x16_f16(aml0, bxh[ks], a0, 0, 0, 0);
                a1 = __builtin_amdgcn_mfma_f32_32x32x16_f16(aml1, bxh[ks], a1, 0, 0, 0);
            }
            u32 h0[8], h1[8];
            #pragma unroll
            for (int j = 0; j < 8; ++j) {
                h0[j] = pk2h(a0[2*j], a0[2*j+1]);
                h1[j] = pk2h(a1[2*j], a1[2*j+1]);
            }
            qh[ob0*2+0] = make_bfrag(h0[0], h0[1], h0[2], h0[3], g32);
            qh[ob0*2+1] = make_bfrag(h0[4], h0[5], h0[6], h0[7], g32);
            qh[ob1*2+0] = make_bfrag(h1[0], h1[1], h1[2], h1[3], g32);
            qh[ob1*2+1] = make_bfrag(h1[4], h1[5], h1[6], h1[7], g32);
        }
    }

    f32x16 vt[6];
    #pragma unroll
    for (int ob = 0; ob < 6; ++ob)
        #pragma unroll
        for (int i = 0; i < 16; ++i) vt[ob][i] = 0.0f;

    float run_m = -3.0e38f, run_l = 0.0f;

    uint4 ld[6];
    auto load_tile = [&](int mt) {
        const int krow0 = koff + mt*32;
        #pragma unroll
        for (int i = 0; i < 6; ++i) {
            int c = tid + i*256;
            const u16* gp;
            if (c < 768) {
                int rr = c/24, cc = c - rr*24;
                gp = xh_g + (size_t)(krow0 + rr)*D + cc*8;
            } else {
                int c3 = c - 768, dd = c3 >> 2, qq = c3 & 3;
                gp = xT_g + (size_t)(mtb + mt)*6144 + dd*32 + qq*8;
            }
            ld[i] = *reinterpret_cast<const uint4*>(gp);
        }
    };
    auto store_tile = [&](int xb) {
        #pragma unroll
        for (int i = 0; i < 6; ++i) {
            int c = tid + i*256;
            u16* lp;
            if (c < 768) {
                int rr = c/24, cc = c - rr*24;  lp = &sXh[rr*200 + cc*8];
            } else {
                int c3 = c - 768, dd = c3 >> 2, qq = c3 & 3;  lp = &sXT[xb][dd*40 + qq*8];
            }
            *reinterpret_cast<uint4*>(lp) = ld[i];
        }
    };
    auto SCORES = [&](f32x16 &sOut) {
        f32x16 s0, s1;
        #pragma unroll
        for (int i = 0; i < 16; ++i) { s0[i] = 0.0f; s1[i] = 0.0f; }
        __builtin_amdgcn_s_setprio(1);
        #pragma unroll
        for (int ks = 0; ks < 6; ++ks) {
            f16x8 ah0 = *reinterpret_cast<const f16x8*>(&sXh[l31*200 + ks*16 + g32*8]);
            f16x8 ah1 = *reinterpret_cast<const f16x8*>(&sXh[l31*200 + (ks+6)*16 + g32*8]);
            s0 = __builtin_amdgcn_mfma_f32_32x32x16_f16(ah0, qh[ks],   s0, 0, 0, 0);
            s1 = __builtin_amdgcn_mfma_f32_32x32x16_f16(ah1, qh[ks+6], s1, 0, 0, 0);
        }
        __builtin_amdgcn_s_setprio(0);
        #pragma unroll
        for (int i = 0; i < 16; ++i) sOut[i] = s0[i] + s1[i];
    };
    auto SOFTMAX = [&](f32x16 &sIn, f16x8 &pf0, f16x8 &pf1) {
        float tmax = sIn[0];
        #pragma unroll
        for (int i = 1; i < 16; ++i) tmax = fmaxf(tmax, sIn[i]);
        tmax = fmaxf(tmax, __shfl_xor(tmax, 32));
        if (__any(tmax > run_m + 8.0f)) {       // defer-rescale (T13)
            float nm = fmaxf(run_m, tmax);
            float rs = __expf(run_m - nm);
            #pragma unroll
            for (int ob = 0; ob < 6; ++ob)
                #pragma unroll
                for (int i = 0; i < 16; ++i) vt[ob][i] *= rs;
            run_l *= rs;
            run_m = nm;
        }
        float psum = 0.0f;
        u32 q[8];
        #pragma unroll
        for (int j = 0; j < 8; ++j) {
            float p0 = __expf(sIn[2*j]   - run_m);
            float p1 = __expf(sIn[2*j+1] - run_m);
            psum += p0 + p1;
            q[j] = pk2h_rtz(p0, p1);
        }
        psum += __shfl_xor(psum, 32);
        run_l += psum;
        pf0 = make_bfrag(q[0], q[1], q[2], q[3], g32);
        pf1 = make_bfrag(q[4], q[5], q[6], q[7], g32);
    };
    auto PV = [&](int bp, f16x8 pf0, f16x8 pf1) {
        __builtin_amdgcn_s_setprio(1);
        #pragma unroll
        for (int ob = 0; ob < 6; ++ob) {
            f16x8 a0 = *reinterpret_cast<const f16x8*>(&sXT[bp][(ob*32 + l31)*40 + g32*8]);
            f16x8 a1 = *reinterpret_cast<const f16x8*>(&sXT[bp][(ob*32 + l31)*40 + 16 + g32*8]);
            vt[ob] = __builtin_amdgcn_mfma_f32_32x32x16_f16(a0, pf0, vt[ob], 0, 0, 0);
            vt[ob] = __builtin_amdgcn_mfma_f32_32x32x16_f16(a1, pf1, vt[ob], 0, 0, 0);
        }
        __builtin_amdgcn_s_setprio(0);
    };

    f32x16 sA, sB;

    // ---- pipeline prologue ----
    load_tile(0); store_tile(0); __syncthreads();   // tile0 -> sXh, sXT[0]
    load_tile(1);
    SCORES(sA);                                     // scores(0) from sXh
    __syncthreads();                                // all waves done reading sXh
    store_tile(1);                                  // tile1 -> sXh, sXT[1]
    __syncthreads();

    // STEP(cur): SCORES(cur) from sXh; softmax+PV(cur-1); store tile cur+1
    auto STEP = [&](int cur, f32x16 &sCur, f32x16 &sPrev) {
        if (cur < 31) load_tile(cur + 1);
        SCORES(sCur);                        // MFMA(cur) issues...
        f16x8 pf0, pf1;
        SOFTMAX(sPrev, pf0, pf1);            // ...while VALU does softmax(prev)
        PV((cur - 1) & 1, pf0, pf1);
        __syncthreads();                     // SCORES+PV done block-wide
        if (cur < 31) {
            store_tile((cur + 1) & 1);       // sXh + sXT[(cur+1)&1]
            __syncthreads();
        }
    };

    #pragma unroll 1
    for (int m2 = 1; m2 <= 29; m2 += 2) {
        STEP(m2,     sB, sA);
        STEP(m2 + 1, sA, sB);
    }
    STEP(31, sB, sA);                        // scores(31), softmax+PV(30)
    // ---- epilogue: softmax + PV of tile31 (in sXT[1]) ----
    {
        f16x8 pf0, pf1;
        SOFTMAX(sB, pf0, pf1);
        PV(1, pf0, pf1);
    }

    // --- normalize ---
    float inv = 1.0f / run_l;
    #pragma unroll
    for (int ob = 0; ob < 6; ++ob)
        #pragma unroll
        for (int i = 0; i < 16; ++i) vt[ob][i] *= inv;

    // --- combine: Y^T[dout][n] = sum_din WT[dout][din] * Vt^T[din][n] ---
    const u16* wbase = wtp_g + (size_t)th*36864;
    f32x16 y[6];
    #pragma unroll
    for (int ob = 0; ob < 6; ++ob)
        #pragma unroll
        for (int i = 0; i < 16; ++i) y[ob][i] = 0.0f;

    #pragma unroll
    for (int ob = 0; ob < 6; ++ob) {
        u32 qq[8];
        #pragma unroll
        for (int j = 0; j < 8; ++j) qq[j] = pk2h_rtz(vt[ob][2*j], vt[ob][2*j+1]);
        #pragma unroll
        for (int half = 0; half < 2; ++half) {
            int ks = ob*2 + half;
            f16x8 bfr = half ? make_bfrag(qq[4], qq[5], qq[6], qq[7], g32)
                             : make_bfrag(qq[0], qq[1], qq[2], qq[3], g32);
            #pragma unroll
            for (int ob2 = 0; ob2 < 6; ++ob2) {
                f16x8 a = *reinterpret_cast<const f16x8*>(
                    wbase + ((((size_t)ob2*12) + ks)*64 + lane)*8);
                y[ob2] = __builtin_amdgcn_mfma_f32_32x32x16_f16(a, bfr, y[ob2], 0, 0, 0);
            }
        }
    }

    // --- write partial Y[t][h][n][dout] (fp16) ---
    u16* yrow = y_g + ((size_t)th*1024 + n0 + l31)*D;
    #pragma unroll
    for (int ob = 0; ob < 6; ++ob)
        #pragma unroll
        for (int rq = 0; rq < 4; ++rq) {
            uint2 v;
            v.x = pk2h_rtz(y[ob][rq*4+0], y[ob][rq*4+1]);
            v.y = pk2h_rtz(y[ob][rq*4+2], y[ob][rq*4+3]);
            *reinterpret_cast<uint2*>(yrow + ob*32 + rq*8 + g32*4) = v;
        }
}

// =====================================================================
// Reduce: out[p*1024+n][d] = sum_{t in pair, h} y[t][h][n][d]  (fp16 in)
// =====================================================================
__global__ __launch_bounds__(512)
void reduce_y(const u16* __restrict__ y_g, float* __restrict__ out)
{
    int gi = blockIdx.x*512 + threadIdx.x;     // < 2048*192/8
    int n = gi / 24, c = gi - n*24;
    int p = n >> 10, nn = n & 1023;
    float acc[8];
    #pragma unroll
    for (int j = 0; j < 8; ++j) acc[j] = 0.0f;
    #pragma unroll
    for (int k = 0; k < 32; ++k) {
        int tcur = p*2 + (k >> 4), hh = k & 15;
        uint4 v = *reinterpret_cast<const uint4*>(
            y_g + ((size_t)((tcur*16+hh)*1024 + nn))*D + c*8);
        u32 w[4] = {v.x, v.y, v.z, v.w};
        #pragma unroll
        for (int j = 0; j < 4; ++j) {
            acc[2*j]   += h2f((u16)(w[j] & 0xffffu));
            acc[2*j+1] += h2f((u16)(w[j] >> 16));
        }
    }
    float* op = out + (size_t)n*D + c*8;
    float4 o0 = {acc[0], acc[1], acc[2], acc[3]};
    float4 o1 = {acc[4], acc[5], acc[6], acc[7]};
    *reinterpret_cast<float4*>(op)     = o0;
    *reinterpret_cast<float4*>(op + 4) = o1;
}

// =====================================================================
// Fallback (round-1 fp32 kernel) if ws too small
// =====================================================================
__global__ __launch_bounds__(256, 2)
void attn_fused_fb(const float* __restrict__ x,
                const float* __restrict__ Muu, const float* __restrict__ Mdd,
                const float* __restrict__ Mud, const float* __restrict__ Mdu,
                const float* __restrict__ Auu, const float* __restrict__ Add,
                const float* __restrict__ Aud, const float* __restrict__ Adu,
                float* __restrict__ out)
{
    const int nt  = blockIdx.x;
    const int h   = blockIdx.y;
    const int t   = blockIdx.z;
    const int tid = threadIdx.x;
    const float* qb = (t <= 1) ? x : x + (size_t)NUP*D;
    const float* kb = (t == 0 || t == 3) ? x : x + (size_t)NUP*D;
    const float* Mp = (t==0)?Muu:(t==1)?Mud:(t==2)?Mdd:Mdu;
    const float* Ap = (t==0)?Auu:(t==1)?Aud:(t==2)?Add:Adu;
    const float* Mh = Mp + (size_t)h*32*D;
    const float* Ah = Ap + (size_t)h*32*D;
    float* ob = out + ((t>=2) ? (size_t)NUP*D : 0);

    __shared__ float sK[32*196];
    __shared__ float sQM[32*196];
    __shared__ float sS[32*33];
    __shared__ float sTmp[32*8];
    __shared__ float sR[32];
    __shared__ float sMaxRun[32];
    __shared__ float sSumRun[32];

    if (tid < 32) { sMaxRun[tid] = -3.0e38f; sSumRun[tid] = 0.0f; }
    for (int i = tid; i < 32*D/4; i += 256)
        reinterpret_cast<float4*>(sK)[i] = reinterpret_cast<const float4*>(Mh)[i];
    __syncthreads();

    #pragma unroll
    for (int kk = 0; kk < 4; ++kk) {
        int p = tid + kk*256;
        int n = p >> 5, g = p & 31;
        const float* qrow = qb + (size_t)(nt*32 + n)*D;
        float acc[6] = {0,0,0,0,0,0};
        for (int f = 0; f < 32; ++f) {
            const float* qf = qrow + f*6;
            const float* mf = sK + f*D + g*6;
            #pragma unroll
            for (int z = 0; z < 3; ++z) {
                float q0 = qf[2*z], q1 = qf[2*z+1];
                float m0 = mf[2*z], m1 = mf[2*z+1];
                acc[2*z]   += q0*m0 - q1*m1;
                acc[2*z+1] += q1*m0 + q0*m1;
            }
        }
        #pragma unroll
        for (int j = 0; j < 6; ++j) sQM[n*196 + g*6 + j] = acc[j];
    }

    const int gn = tid >> 5;
    const int cg = tid & 31;
    const int cbase = cg*6;
    float vacc[4][6];
    #pragma unroll
    for (int a = 0; a < 4; ++a)
        #pragma unroll
        for (int b = 0; b < 6; ++b) vacc[a][b] = 0.0f;

    const int txm = tid & 15, tyn = tid >> 4;

    for (int mt = 0; mt < 32; ++mt) {
        __syncthreads();
        for (int i = tid; i < 32*(D/4); i += 256) {
            int row = i / (D/4), j = i - row*(D/4);
            float4 v = reinterpret_cast<const float4*>(kb + (size_t)(mt*32 + row)*D)[j];
            *reinterpret_cast<float4*>(&sK[row*196 + j*4]) = v;
        }
        __syncthreads();

        float a00=0,a01=0,a10=0,a11=0;
        {
            const float* q0p = &sQM[tyn*196];
            const float* q1p = &sQM[(tyn+16)*196];
            const float* k0p = &sK[txm*196];
            const float* k1p = &sK[(txm+16)*196];
            for (int k = 0; k < D; k += 4) {
                float4 qa = *reinterpret_cast<const float4*>(q0p+k);
                float4 qc = *reinterpret_cast<const float4*>(q1p+k);
                float4 ka = *reinterpret_cast<const float4*>(k0p+k);
                float4 kc = *reinterpret_cast<const float4*>(k1p+k);
                a00 += qa.x*ka.x + qa.y*ka.y + qa.z*ka.z + qa.w*ka.w;
                a01 += qa.x*kc.x + qa.y*kc.y + qa.z*kc.z + qa.w*kc.w;
                a10 += qc.x*ka.x + qc.y*ka.y + qc.z*ka.z + qc.w*ka.w;
                a11 += qc.x*kc.x + qc.y*kc.y + qc.z*kc.z + qc.w*kc.w;
            }
        }
        sS[tyn*33 + txm]          = a00;
        sS[tyn*33 + txm+16]       = a01;
        sS[(tyn+16)*33 + txm]     = a10;
        sS[(tyn+16)*33 + txm+16]  = a11;
        __syncthreads();

        const int srow = tid >> 3, sj = tid & 7;
        {
            const float* r = &sS[srow*33];
            float mx = fmaxf(fmaxf(r[sj], r[sj+8]), fmaxf(r[sj+16], r[sj+24]));
            sTmp[srow*8 + sj] = mx;
        }
        __syncthreads();
        if (tid < 32) {
            float mx = sTmp[tid*8];
            #pragma unroll
            for (int j = 1; j < 8; ++j) mx = fmaxf(mx, sTmp[tid*8+j]);
            float om = sMaxRun[tid];
            float nm = fmaxf(om, mx);
            sR[tid] = __expf(om - nm);
            sMaxRun[tid] = nm;
        }
        __syncthreads();
        {
            float nm = sMaxRun[srow];
            float* r = &sS[srow*33];
            float p0 = __expf(r[sj]    - nm);
            float p1 = __expf(r[sj+8]  - nm);
            float p2 = __expf(r[sj+16] - nm);
            float p3 = __expf(r[sj+24] - nm);
            r[sj] = p0; r[sj+8] = p1; r[sj+16] = p2; r[sj+24] = p3;
            sTmp[srow*8+sj] = p0+p1+p2+p3;
        }
        __syncthreads();
        if (tid < 32) {
            float s = 0.0f;
            #pragma unroll
            for (int j = 0; j < 8; ++j) s += sTmp[tid*8+j];
            sSumRun[tid] = sSumRun[tid]*sR[tid] + s;
        }
        {
            float r0 = sR[gn*4+0], r1 = sR[gn*4+1], r2 = sR[gn*4+2], r3 = sR[gn*4+3];
            #pragma unroll
            for (int b = 0; b < 6; ++b) { vacc[0][b]*=r0; vacc[1][b]*=r1; vacc[2][b]*=r2; vacc[3][b]*=r3; }
            for (int m = 0; m < 32; ++m) {
                float p0 = sS[(gn*4+0)*33+m];
                float p1 = sS[(gn*4+1)*33+m];
                float p2 = sS[(gn*4+2)*33+m];
                float p3 = sS[(gn*4+3)*33+m];
                const float* kr = &sK[m*196 + cbase];
                #pragma unroll
                for (int b = 0; b < 6; ++b) {
                    float kv = kr[b];
                    vacc[0][b] += p0*kv;
                    vacc[1][b] += p1*kv;
                    vacc[2][b] += p2*kv;
                    vacc[3][b] += p3*kv;
                }
            }
        }
    }

    __syncthreads();
    {
        float i0 = 1.0f/sSumRun[gn*4+0], i1 = 1.0f/sSumRun[gn*4+1];
        float i2 = 1.0f/sSumRun[gn*4+2], i3 = 1.0f/sSumRun[gn*4+3];
        #pragma unroll
        for (int b = 0; b < 6; ++b) {
            sQM[(gn*4+0)*196 + cbase + b] = vacc[0][b]*i0;
            sQM[(gn*4+1)*196 + cbase + b] = vacc[1][b]*i1;
            sQM[(gn*4+2)*196 + cbase + b] = vacc[2][b]*i2;
            sQM[(gn*4+3)*196 + cbase + b] = vacc[3][b]*i3;
        }
    }
    for (int i = tid; i < 32*D/4; i += 256)
        reinterpret_cast<float4*>(sK)[i] = reinterpret_cast<const float4*>(Ah)[i];
    __syncthreads();

    #pragma unroll
    for (int kk = 0; kk < 4; ++kk) {
        int p = tid + kk*256;
        int n = p >> 5, g = p & 31;
        float acc[6] = {0,0,0,0,0,0};
        const float* vb = &sQM[n*196];
        const float* ab = &sK[g*D];
        for (int f = 0; f < 32; ++f) {
            const float* vf = vb + f*6;
            const float* af = ab + f*6;
            #pragma unroll
            for (int z = 0; z < 3; ++z) {
                float V0 = vf[2*z], V1 = vf[2*z+1];
                float A0 = af[2*z], A1 = af[2*z+1];
                acc[2*z]   += A0*V0 - A1*V1;
                acc[2*z+1] += A0*V1 + A1*V0;
            }
        }
        float* op = ob + (size_t)(nt*32 + n)*D + g*6;
        #pragma unroll
        for (int j = 0; j < 6; ++j) atomicAdd(op + j, acc[j]);
    }
}

extern "C" void kernel_launch(void* const* d_in, const int* in_sizes, int n_in,
                              void* d_out, int out_size, void* d_ws, size_t ws_size,
                              hipStream_t stream) {
    const float* x   = (const float*)d_in[0];
    const float* Muu = (const float*)d_in[1];
    const float* Mdd = (const float*)d_in[2];
    const float* Mud = (const float*)d_in[3];
    const float* Mdu = (const float*)d_in[4];
    const float* Auu = (const float*)d_in[5];
    const float* Add = (const float*)d_in[6];
    const float* Aud = (const float*)d_in[7];
    const float* Adu = (const float*)d_in[8];
    float* outp = (float*)d_out;

    if (ws_size >= WS_NEED) {
        char* ws = (char*)d_ws;
        u16* xh  = (u16*)(ws + XH_OFF);
        u16* xl  = (u16*)(ws + XL_OFF);
        u16* xT  = (u16*)(ws + XT_OFF);
        u16* wtp = (u16*)(ws + WTP_OFF);
        u16* mth = (u16*)(ws + MTH_OFF);
        u16* mtl = (u16*)(ws + MTL_OFF);
        u16* y   = (u16*)(ws + Y_OFF);

        prep_all<<<5376, 512, 0, stream>>>(x, Muu, Mdd, Mud, Mdu,
                                           Auu, Add, Aud, Adu,
                                           xh, xl, xT, wtp, mth, mtl);
        attn_mfma<<<dim3(8, 16, 4), 256, 0, stream>>>(xh, xl, xT, wtp, mth, mtl, y);
        reduce_y<<<96, 512, 0, stream>>>(y, outp);
    } else {
        (void)hipMemsetAsync(d_out, 0, (size_t)out_size * sizeof(float), stream);
        attn_fused_fb<<<dim3(32, 16, 4), 256, 0, stream>>>(x, Muu, Mdd, Mud, Mdu,
                                                           Auu, Add, Aud, Adu, outp);
    }
}

// Round 14
// 154.434 us; speedup vs baseline: 1.1063x; 1.1063x over previous
//
#include <hip/hip_runtime.h>
#include <hip/hip_bf16.h>

typedef unsigned short u16;
typedef unsigned int   u32;
typedef _Float16 f16x8 __attribute__((ext_vector_type(8)));
typedef float    f32x16 __attribute__((ext_vector_type(16)));

#define HEADS 16
#define D     192
#define NUP   1024

// ---- workspace layout (bytes) ----
#define XB       (2048ull*192*2)               // 786432
#define XH_OFF   0ull
#define XL_OFF   (XH_OFF + XB)
#define XT_OFF   (XL_OFF + XB)
#define WM_BYTES (64ull*192*192*2)             // 4718592
#define WTP_OFF  (XT_OFF + XB)
#define MTH_OFF  (WTP_OFF + WM_BYTES)
#define MTL_OFF  (MTH_OFF + WM_BYTES)
#define Y_BYTES  (64ull*1024*192*2)            // 25165824 (fp16)
#define Y_OFF    (MTH_OFF + 2*WM_BYTES)
#define WS_NEED  (Y_OFF + Y_BYTES)             // 41680896

__device__ __forceinline__ u16 f2h(float v) {
    _Float16 h = (_Float16)v;
    return __builtin_bit_cast(u16, h);
}
__device__ __forceinline__ float h2f(u16 v) {
    return (float)__builtin_bit_cast(_Float16, v);
}
__device__ __forceinline__ u32 pk2h(float a, float b) {      // RNE
    return (u32)f2h(a) | ((u32)f2h(b) << 16);
}
__device__ __forceinline__ u32 pk2h_rtz(float a, float b) {  // 1-instr packed
    auto r = __builtin_amdgcn_cvt_pkrtz(a, b);
    return __builtin_bit_cast(u32, r);
}

// =====================================================================
// helper: assemble B-fragment (32x32x16) from 4 packed-pair u32s in
// D-frag order (m = (r&3)+8*(r>>2)+4*(lane>>5)) via half-swap (shfl —
// HW-verified R2..R12)
// =====================================================================
__device__ __forceinline__ f16x8 make_bfrag(u32 q0, u32 q1, u32 q2, u32 q3, bool hi) {
    u32 s0 = (u32)__shfl_xor((int)q0, 32);
    u32 s1 = (u32)__shfl_xor((int)q1, 32);
    u32 s2 = (u32)__shfl_xor((int)q2, 32);
    u32 s3 = (u32)__shfl_xor((int)q3, 32);
    uint4 w;
    w.x = hi ? s2 : q0;  w.y = hi ? s3 : q1;
    w.z = hi ? q2 : s0;  w.w = hi ? q3 : s1;
    return __builtin_bit_cast(f16x8, w);
}

// =====================================================================
// Prep ALL (merged): blocks [0,768) do x->xh,xl,xT ; rest build WT/MT.
// =====================================================================
__global__ __launch_bounds__(512)
void prep_all(const float* __restrict__ x,
              const float* __restrict__ Muu, const float* __restrict__ Mdd,
              const float* __restrict__ Mud, const float* __restrict__ Mdu,
              const float* __restrict__ Auu, const float* __restrict__ Add,
              const float* __restrict__ Aud, const float* __restrict__ Adu,
              u16* __restrict__ xh, u16* __restrict__ xl, u16* __restrict__ xT,
              u16* __restrict__ wtp, u16* __restrict__ mth, u16* __restrict__ mtl)
{
    int b = blockIdx.x;
    if (b < 768) {
        int i = b*512 + threadIdx.x;           // < 2048*192
        float v = x[i];
        int n = i / D, d = i - n*D;
        u16 hi = f2h(v);
        xh[i] = hi;
        xl[i] = f2h(v - h2f(hi));
        xT[(size_t)(n >> 5)*6144 + d*32 + (n & 31)] = hi;
        return;
    }
    int idx = (b - 768)*512 + threadIdx.x;     // < 64*36864
    int th = idx / 36864, r = idx - th*36864;
    int dout = r / 192, din = r - dout*192;
    int t = th >> 4, h = th & 15;
    const float* Ap = (t==0)?Auu:(t==1)?Aud:(t==2)?Add:Adu;
    const float* Mp = (t==0)?Muu:(t==1)?Mud:(t==2)?Mdd:Mdu;
    int g = dout / 6, zc = dout - g*6, z = zc >> 1, b0 = zc & 1;
    int f = din / 6,  zb = din - f*6,  z2 = zb >> 1, b1 = zb & 1;

    float wv = 0.0f, mv = 0.0f;
    if (z2 == z) {
        const float* a = Ap + (((size_t)h*32 + g)*32 + f)*6 + z*2;
        float A0 = a[0], A1 = a[1];
        wv = (b0 == 0) ? (b1 == 0 ? A0 : -A1) : (b1 == 0 ? A1 : A0);
        const float* m = Mp + (((size_t)h*32 + f)*32 + g)*6 + z*2;
        float M0 = m[0], M1 = m[1];
        mv = (b0 == 0) ? (b1 == 0 ? M0 : -M1) : (b1 == 0 ? M1 : M0);
    }
    int ob = dout >> 5, l31 = dout & 31;
    int ks = din >> 4, kr = din & 15, g32 = kr >> 3, j = kr & 7;
    size_t pidx = ((((size_t)th*6 + ob)*12 + ks)*64 + g32*32 + l31)*8 + j;
    wtp[pidx] = f2h(wv);
    u16 mh = f2h(mv);
    mth[pidx] = mh;
    mtl[pidx] = f2h(mv - h2f(mh));
}

// =====================================================================
// Main fused kernel — 4 waves x 32 q-rows = 128 rows, 256 threads,
// grid (8,16,4) = 512 blocks = 2 independent blocks/CU (m114 overlap).
// LDS: ONLY sXh double-buffered (25.6 KB). PV A-operands straight from
// xT_g (L2-resident 393 KB working set, fully coalesced). One barrier
// per iteration; store-before-barrier into the idle buffer.
// =====================================================================
__global__ __launch_bounds__(256, 2)
void attn_mfma(const u16* __restrict__ xh_g,  const u16* __restrict__ xl_g,
               const u16* __restrict__ xT_g,  const u16* __restrict__ wtp_g,
               const u16* __restrict__ mth_g, const u16* __restrict__ mtl_g,
               u16* __restrict__ y_g)
{
    const int nt = blockIdx.x, h = blockIdx.y, t = blockIdx.z;
    const int tid  = threadIdx.x;
    const int lane = tid & 63;
    const int l31  = lane & 31;
    const int g32  = lane >> 5;
    const int th   = t*16 + h;
    const int n0   = nt*128 + (tid >> 6)*32;
    const int qoff = (t <= 1) ? 0 : NUP;             // q-side rows
    const int koff = (t == 1 || t == 2) ? NUP : 0;   // k/v-side rows
    const int mtb  = koff >> 5;

    __shared__ u16 sXh[2][32*200];

    // ---- prologue: QM B-fragments via MFMA (3-term fp16 split) ----
    f16x8 qh[12];
    {
        f16x8 bxh[12], bxl[12];
        const u16* xrh = xh_g + (size_t)(qoff + n0 + l31)*D;
        const u16* xrl = xl_g + (size_t)(qoff + n0 + l31)*D;
        #pragma unroll
        for (int ks = 0; ks < 12; ++ks) {
            bxh[ks] = *reinterpret_cast<const f16x8*>(xrh + ks*16 + g32*8);
            bxl[ks] = *reinterpret_cast<const f16x8*>(xrl + ks*16 + g32*8);
        }
        const u16* mthb = mth_g + (size_t)th*36864;
        const u16* mtlb = mtl_g + (size_t)th*36864;
        #pragma unroll
        for (int obp = 0; obp < 3; ++obp) {      // 2 obs in flight for ILP
            const int ob0 = obp*2, ob1 = obp*2 + 1;
            f32x16 a0, a1;
            #pragma unroll
            for (int i = 0; i < 16; ++i) { a0[i] = 0.0f; a1[i] = 0.0f; }
            #pragma unroll
            for (int ks = 0; ks < 12; ++ks) {
                size_t fo0 = (((size_t)ob0*12 + ks)*64 + lane)*8;
                size_t fo1 = (((size_t)ob1*12 + ks)*64 + lane)*8;
                f16x8 amh0 = *reinterpret_cast<const f16x8*>(mthb + fo0);
                f16x8 aml0 = *reinterpret_cast<const f16x8*>(mtlb + fo0);
                f16x8 amh1 = *reinterpret_cast<const f16x8*>(mthb + fo1);
                f16x8 aml1 = *reinterpret_cast<const f16x8*>(mtlb + fo1);
                a0 = __builtin_amdgcn_mfma_f32_32x32x16_f16(amh0, bxh[ks], a0, 0, 0, 0);
                a1 = __builtin_amdgcn_mfma_f32_32x32x16_f16(amh1, bxh[ks], a1, 0, 0, 0);
                a0 = __builtin_amdgcn_mfma_f32_32x32x16_f16(amh0, bxl[ks], a0, 0, 0, 0);
                a1 = __builtin_amdgcn_mfma_f32_32x32x16_f16(amh1, bxl[ks], a1, 0, 0, 0);
                a0 = __builtin_amdgcn_mfma_f32_32x32x16_f16(aml0, bxh[ks], a0, 0, 0, 0);
                a1 = __builtin_amdgcn_mfma_f32_32x32x16_f16(aml1, bxh[ks], a1, 0, 0, 0);
            }
            u32 h0[8], h1[8];
            #pragma unroll
            for (int j = 0; j < 8; ++j) {
                h0[j] = pk2h(a0[2*j], a0[2*j+1]);
                h1[j] = pk2h(a1[2*j], a1[2*j+1]);
            }
            qh[ob0*2+0] = make_bfrag(h0[0], h0[1], h0[2], h0[3], g32);
            qh[ob0*2+1] = make_bfrag(h0[4], h0[5], h0[6], h0[7], g32);
            qh[ob1*2+0] = make_bfrag(h1[0], h1[1], h1[2], h1[3], g32);
            qh[ob1*2+1] = make_bfrag(h1[4], h1[5], h1[6], h1[7], g32);
        }
    }

    f32x16 vt[6];
    #pragma unroll
    for (int ob = 0; ob < 6; ++ob)
        #pragma unroll
        for (int i = 0; i < 16; ++i) vt[ob][i] = 0.0f;

    float run_m = -3.0e38f, run_l = 0.0f;

    uint4 ld[3];
    auto load_tile = [&](int mt) {          // xh rows only: 768 chunks
        const int krow0 = koff + mt*32;
        #pragma unroll
        for (int i = 0; i < 3; ++i) {
            int c = tid + i*256;
            int rr = c/24, cc = c - rr*24;
            ld[i] = *reinterpret_cast<const uint4*>(
                xh_g + (size_t)(krow0 + rr)*D + cc*8);
        }
    };
    auto store_tile = [&](int xb) {
        #pragma unroll
        for (int i = 0; i < 3; ++i) {
            int c = tid + i*256;
            int rr = c/24, cc = c - rr*24;
            *reinterpret_cast<uint4*>(&sXh[xb][rr*200 + cc*8]) = ld[i];
        }
    };
    auto SCORES = [&](int xb, f32x16 &sOut) {
        f32x16 s0, s1;
        #pragma unroll
        for (int i = 0; i < 16; ++i) { s0[i] = 0.0f; s1[i] = 0.0f; }
        __builtin_amdgcn_s_setprio(1);
        #pragma unroll
        for (int ks = 0; ks < 6; ++ks) {
            f16x8 ah0 = *reinterpret_cast<const f16x8*>(&sXh[xb][l31*200 + ks*16 + g32*8]);
            f16x8 ah1 = *reinterpret_cast<const f16x8*>(&sXh[xb][l31*200 + (ks+6)*16 + g32*8]);
            s0 = __builtin_amdgcn_mfma_f32_32x32x16_f16(ah0, qh[ks],   s0, 0, 0, 0);
            s1 = __builtin_amdgcn_mfma_f32_32x32x16_f16(ah1, qh[ks+6], s1, 0, 0, 0);
        }
        __builtin_amdgcn_s_setprio(0);
        #pragma unroll
        for (int i = 0; i < 16; ++i) sOut[i] = s0[i] + s1[i];
    };
    auto SOFTMAX = [&](f32x16 &sIn, f16x8 &pf0, f16x8 &pf1) {
        float tmax = sIn[0];
        #pragma unroll
        for (int i = 1; i < 16; ++i) tmax = fmaxf(tmax, sIn[i]);
        tmax = fmaxf(tmax, __shfl_xor(tmax, 32));
        if (__any(tmax > run_m + 8.0f)) {       // defer-rescale (T13)
            float nm = fmaxf(run_m, tmax);
            float rs = __expf(run_m - nm);
            #pragma unroll
            for (int ob = 0; ob < 6; ++ob)
                #pragma unroll
                for (int i = 0; i < 16; ++i) vt[ob][i] *= rs;
            run_l *= rs;
            run_m = nm;
        }
        float psum = 0.0f;
        u32 q[8];
        #pragma unroll
        for (int j = 0; j < 8; ++j) {
            float p0 = __expf(sIn[2*j]   - run_m);
            float p1 = __expf(sIn[2*j+1] - run_m);
            psum += p0 + p1;
            q[j] = pk2h_rtz(p0, p1);
        }
        psum += __shfl_xor(psum, 32);
        run_l += psum;
        pf0 = make_bfrag(q[0], q[1], q[2], q[3], g32);
        pf1 = make_bfrag(q[4], q[5], q[6], q[7], g32);
    };
    auto PV_g = [&](int tile, f16x8 pf0, f16x8 pf1) {   // A from xT_g (L2)
        const u16* xtb = xT_g + (size_t)(mtb + tile)*6144;
        __builtin_amdgcn_s_setprio(1);
        #pragma unroll
        for (int ob = 0; ob < 6; ++ob) {
            f16x8 a0 = *reinterpret_cast<const f16x8*>(xtb + (ob*32 + l31)*32 + g32*8);
            f16x8 a1 = *reinterpret_cast<const f16x8*>(xtb + (ob*32 + l31)*32 + 16 + g32*8);
            vt[ob] = __builtin_amdgcn_mfma_f32_32x32x16_f16(a0, pf0, vt[ob], 0, 0, 0);
            vt[ob] = __builtin_amdgcn_mfma_f32_32x32x16_f16(a1, pf1, vt[ob], 0, 0, 0);
        }
        __builtin_amdgcn_s_setprio(0);
    };

    f32x16 sA, sB;

    // ---- pipeline prologue ----
    load_tile(0); store_tile(0); __syncthreads();   // tile0 -> sXh[0]
    load_tile(1);
    SCORES(0, sA);                                  // scores(0)
    store_tile(1);                                  // tile1 -> sXh[1]
    __syncthreads();

    // STEP(cur): SCORES(cur) from sXh[cur&1]; softmax+PV(cur-1);
    // store tile cur+1 into sXh[(cur+1)&1] (idle buffer); one barrier.
    auto STEP = [&](int cur, f32x16 &sCur, f32x16 &sPrev) {
        if (cur < 31) load_tile(cur + 1);
        SCORES(cur & 1, sCur);               // MFMA(cur) issues...
        f16x8 pf0, pf1;
        SOFTMAX(sPrev, pf0, pf1);            // ...while VALU does softmax(prev)
        PV_g(cur - 1, pf0, pf1);
        if (cur < 31) store_tile((cur + 1) & 1);
        __syncthreads();
    };

    #pragma unroll 1
    for (int m2 = 1; m2 <= 29; m2 += 2) {
        STEP(m2,     sB, sA);
        STEP(m2 + 1, sA, sB);
    }
    STEP(31, sB, sA);                        // scores(31), softmax+PV(30)
    // ---- epilogue: softmax + PV of tile31 ----
    {
        f16x8 pf0, pf1;
        SOFTMAX(sB, pf0, pf1);
        PV_g(31, pf0, pf1);
    }

    // --- normalize ---
    float inv = 1.0f / run_l;
    #pragma unroll
    for (int ob = 0; ob < 6; ++ob)
        #pragma unroll
        for (int i = 0; i < 16; ++i) vt[ob][i] *= inv;

    // --- combine: Y^T[dout][n] = sum_din WT[dout][din] * Vt^T[din][n] ---
    const u16* wbase = wtp_g + (size_t)th*36864;
    f32x16 y[6];
    #pragma unroll
    for (int ob = 0; ob < 6; ++ob)
        #pragma unroll
        for (int i = 0; i < 16; ++i) y[ob][i] = 0.0f;

    #pragma unroll
    for (int ob = 0; ob < 6; ++ob) {
        u32 qq[8];
        #pragma unroll
        for (int j = 0; j < 8; ++j) qq[j] = pk2h_rtz(vt[ob][2*j], vt[ob][2*j+1]);
        #pragma unroll
        for (int half = 0; half < 2; ++half) {
            int ks = ob*2 + half;
            f16x8 bfr = half ? make_bfrag(qq[4], qq[5], qq[6], qq[7], g32)
                             : make_bfrag(qq[0], qq[1], qq[2], qq[3], g32);
            #pragma unroll
            for (int ob2 = 0; ob2 < 6; ++ob2) {
                f16x8 a = *reinterpret_cast<const f16x8*>(
                    wbase + ((((size_t)ob2*12) + ks)*64 + lane)*8);
                y[ob2] = __builtin_amdgcn_mfma_f32_32x32x16_f16(a, bfr, y[ob2], 0, 0, 0);
            }
        }
    }

    // --- write partial Y[t][h][n][dout] (fp16) ---
    u16* yrow = y_g + ((size_t)th*1024 + n0 + l31)*D;
    #pragma unroll
    for (int ob = 0; ob < 6; ++ob)
        #pragma unroll
        for (int rq = 0; rq < 4; ++rq) {
            uint2 v;
            v.x = pk2h_rtz(y[ob][rq*4+0], y[ob][rq*4+1]);
            v.y = pk2h_rtz(y[ob][rq*4+2], y[ob][rq*4+3]);
            *reinterpret_cast<uint2*>(yrow + ob*32 + rq*8 + g32*4) = v;
        }
}

// =====================================================================
// Reduce: out[p*1024+n][d] = sum_{t in pair, h} y[t][h][n][d]  (fp16 in)
// =====================================================================
__global__ __launch_bounds__(512)
void reduce_y(const u16* __restrict__ y_g, float* __restrict__ out)
{
    int gi = blockIdx.x*512 + threadIdx.x;     // < 2048*192/8
    int n = gi / 24, c = gi - n*24;
    int p = n >> 10, nn = n & 1023;
    float acc[8];
    #pragma unroll
    for (int j = 0; j < 8; ++j) acc[j] = 0.0f;
    #pragma unroll
    for (int k = 0; k < 32; ++k) {
        int tcur = p*2 + (k >> 4), hh = k & 15;
        uint4 v = *reinterpret_cast<const uint4*>(
            y_g + ((size_t)((tcur*16+hh)*1024 + nn))*D + c*8);
        u32 w[4] = {v.x, v.y, v.z, v.w};
        #pragma unroll
        for (int j = 0; j < 4; ++j) {
            acc[2*j]   += h2f((u16)(w[j] & 0xffffu));
            acc[2*j+1] += h2f((u16)(w[j] >> 16));
        }
    }
    float* op = out + (size_t)n*D + c*8;
    float4 o0 = {acc[0], acc[1], acc[2], acc[3]};
    float4 o1 = {acc[4], acc[5], acc[6], acc[7]};
    *reinterpret_cast<float4*>(op)     = o0;
    *reinterpret_cast<float4*>(op + 4) = o1;
}

// =====================================================================
// Fallback (round-1 fp32 kernel) if ws too small
// =====================================================================
__global__ __launch_bounds__(256, 2)
void attn_fused_fb(const float* __restrict__ x,
                const float* __restrict__ Muu, const float* __restrict__ Mdd,
                const float* __restrict__ Mud, const float* __restrict__ Mdu,
                const float* __restrict__ Auu, const float* __restrict__ Add,
                const float* __restrict__ Aud, const float* __restrict__ Adu,
                float* __restrict__ out)
{
    const int nt  = blockIdx.x;
    const int h   = blockIdx.y;
    const int t   = blockIdx.z;
    const int tid = threadIdx.x;
    const float* qb = (t <= 1) ? x : x + (size_t)NUP*D;
    const float* kb = (t == 0 || t == 3) ? x : x + (size_t)NUP*D;
    const float* Mp = (t==0)?Muu:(t==1)?Mud:(t==2)?Mdd:Mdu;
    const float* Ap = (t==0)?Auu:(t==1)?Aud:(t==2)?Add:Adu;
    const float* Mh = Mp + (size_t)h*32*D;
    const float* Ah = Ap + (size_t)h*32*D;
    float* ob = out + ((t>=2) ? (size_t)NUP*D : 0);

    __shared__ float sK[32*196];
    __shared__ float sQM[32*196];
    __shared__ float sS[32*33];
    __shared__ float sTmp[32*8];
    __shared__ float sR[32];
    __shared__ float sMaxRun[32];
    __shared__ float sSumRun[32];

    if (tid < 32) { sMaxRun[tid] = -3.0e38f; sSumRun[tid] = 0.0f; }
    for (int i = tid; i < 32*D/4; i += 256)
        reinterpret_cast<float4*>(sK)[i] = reinterpret_cast<const float4*>(Mh)[i];
    __syncthreads();

    #pragma unroll
    for (int kk = 0; kk < 4; ++kk) {
        int p = tid + kk*256;
        int n = p >> 5, g = p & 31;
        const float* qrow = qb + (size_t)(nt*32 + n)*D;
        float acc[6] = {0,0,0,0,0,0};
        for (int f = 0; f < 32; ++f) {
            const float* qf = qrow + f*6;
            const float* mf = sK + f*D + g*6;
            #pragma unroll
            for (int z = 0; z < 3; ++z) {
                float q0 = qf[2*z], q1 = qf[2*z+1];
                float m0 = mf[2*z], m1 = mf[2*z+1];
                acc[2*z]   += q0*m0 - q1*m1;
                acc[2*z+1] += q1*m0 + q0*m1;
            }
        }
        #pragma unroll
        for (int j = 0; j < 6; ++j) sQM[n*196 + g*6 + j] = acc[j];
    }

    const int gn = tid >> 5;
    const int cg = tid & 31;
    const int cbase = cg*6;
    float vacc[4][6];
    #pragma unroll
    for (int a = 0; a < 4; ++a)
        #pragma unroll
        for (int b = 0; b < 6; ++b) vacc[a][b] = 0.0f;

    const int txm = tid & 15, tyn = tid >> 4;

    for (int mt = 0; mt < 32; ++mt) {
        __syncthreads();
        for (int i = tid; i < 32*(D/4); i += 256) {
            int row = i / (D/4), j = i - row*(D/4);
            float4 v = reinterpret_cast<const float4*>(kb + (size_t)(mt*32 + row)*D)[j];
            *reinterpret_cast<float4*>(&sK[row*196 + j*4]) = v;
        }
        __syncthreads();

        float a00=0,a01=0,a10=0,a11=0;
        {
            const float* q0p = &sQM[tyn*196];
            const float* q1p = &sQM[(tyn+16)*196];
            const float* k0p = &sK[txm*196];
            const float* k1p = &sK[(txm+16)*196];
            for (int k = 0; k < D; k += 4) {
                float4 qa = *reinterpret_cast<const float4*>(q0p+k);
                float4 qc = *reinterpret_cast<const float4*>(q1p+k);
                float4 ka = *reinterpret_cast<const float4*>(k0p+k);
                float4 kc = *reinterpret_cast<const float4*>(k1p+k);
                a00 += qa.x*ka.x + qa.y*ka.y + qa.z*ka.z + qa.w*ka.w;
                a01 += qa.x*kc.x + qa.y*kc.y + qa.z*kc.z + qa.w*kc.w;
                a10 += qc.x*ka.x + qc.y*ka.y + qc.z*ka.z + qc.w*ka.w;
                a11 += qc.x*kc.x + qc.y*kc.y + qc.z*kc.z + qc.w*kc.w;
            }
        }
        sS[tyn*33 + txm]          = a00;
        sS[tyn*33 + txm+16]       = a01;
        sS[(tyn+16)*33 + txm]     = a10;
        sS[(tyn+16)*33 + txm+16]  = a11;
        __syncthreads();

        const int srow = tid >> 3, sj = tid & 7;
        {
            const float* r = &sS[srow*33];
            float mx = fmaxf(fmaxf(r[sj], r[sj+8]), fmaxf(r[sj+16], r[sj+24]));
            sTmp[srow*8 + sj] = mx;
        }
        __syncthreads();
        if (tid < 32) {
            float mx = sTmp[tid*8];
            #pragma unroll
            for (int j = 1; j < 8; ++j) mx = fmaxf(mx, sTmp[tid*8+j]);
            float om = sMaxRun[tid];
            float nm = fmaxf(om, mx);
            sR[tid] = __expf(om - nm);
            sMaxRun[tid] = nm;
        }
        __syncthreads();
        {
            float nm = sMaxRun[srow];
            float* r = &sS[srow*33];
            float p0 = __expf(r[sj]    - nm);
            float p1 = __expf(r[sj+8]  - nm);
            float p2 = __expf(r[sj+16] - nm);
            float p3 = __expf(r[sj+24] - nm);
            r[sj] = p0; r[sj+8] = p1; r[sj+16] = p2; r[sj+24] = p3;
            sTmp[srow*8+sj] = p0+p1+p2+p3;
        }
        __syncthreads();
        if (tid < 32) {
            float s = 0.0f;
            #pragma unroll
            for (int j = 0; j < 8; ++j) s += sTmp[tid*8+j];
            sSumRun[tid] = sSumRun[tid]*sR[tid] + s;
        }
        {
            float r0 = sR[gn*4+0], r1 = sR[gn*4+1], r2 = sR[gn*4+2], r3 = sR[gn*4+3];
            #pragma unroll
            for (int b = 0; b < 6; ++b) { vacc[0][b]*=r0; vacc[1][b]*=r1; vacc[2][b]*=r2; vacc[3][b]*=r3; }
            for (int m = 0; m < 32; ++m) {
                float p0 = sS[(gn*4+0)*33+m];
                float p1 = sS[(gn*4+1)*33+m];
                float p2 = sS[(gn*4+2)*33+m];
                float p3 = sS[(gn*4+3)*33+m];
                const float* kr = &sK[m*196 + cbase];
                #pragma unroll
                for (int b = 0; b < 6; ++b) {
                    float kv = kr[b];
                    vacc[0][b] += p0*kv;
                    vacc[1][b] += p1*kv;
                    vacc[2][b] += p2*kv;
                    vacc[3][b] += p3*kv;
                }
            }
        }
    }

    __syncthreads();
    {
        float i0 = 1.0f/sSumRun[gn*4+0], i1 = 1.0f/sSumRun[gn*4+1];
        float i2 = 1.0f/sSumRun[gn*4+2], i3 = 1.0f/sSumRun[gn*4+3];
        #pragma unroll
        for (int b = 0; b < 6; ++b) {
            sQM[(gn*4+0)*196 + cbase + b] = vacc[0][b]*i0;
            sQM[(gn*4+1)*196 + cbase + b] = vacc[1][b]*i1;
            sQM[(gn*4+2)*196 + cbase + b] = vacc[2][b]*i2;
            sQM[(gn*4+3)*196 + cbase + b] = vacc[3][b]*i3;
        }
    }
    for (int i = tid; i < 32*D/4; i += 256)
        reinterpret_cast<float4*>(sK)[i] = reinterpret_cast<const float4*>(Ah)[i];
    __syncthreads();

    #pragma unroll
    for (int kk = 0; kk < 4; ++kk) {
        int p = tid + kk*256;
        int n = p >> 5, g = p & 31;
        float acc[6] = {0,0,0,0,0,0};
        const float* vb = &sQM[n*196];
        const float* ab = &sK[g*D];
        for (int f = 0; f < 32; ++f) {
            const float* vf = vb + f*6;
            const float* af = ab + f*6;
            #pragma unroll
            for (int z = 0; z < 3; ++z) {
                float V0 = vf[2*z], V1 = vf[2*z+1];
                float A0 = af[2*z], A1 = af[2*z+1];
                acc[2*z]   += A0*V0 - A1*V1;
                acc[2*z+1] += A0*V1 + A1*V0;
            }
        }
        float* op = ob + (size_t)(nt*32 + n)*D + g*6;
        #pragma unroll
        for (int j = 0; j < 6; ++j) atomicAdd(op + j, acc[j]);
    }
}

extern "C" void kernel_launch(void* const* d_in, const int* in_sizes, int n_in,
                              void* d_out, int out_size, void* d_ws, size_t ws_size,
                              hipStream_t stream) {
    const float* x   = (const float*)d_in[0];
    const float* Muu = (const float*)d_in[1];
    const float* Mdd = (const float*)d_in[2];
    const float* Mud = (const float*)d_in[3];
    const float* Mdu = (const float*)d_in[4];
    const float* Auu = (const float*)d_in[5];
    const float* Add = (const float*)d_in[6];
    const float* Aud = (const float*)d_in[7];
    const float* Adu = (const float*)d_in[8];
    float* outp = (float*)d_out;

    if (ws_size >= WS_NEED) {
        char* ws = (char*)d_ws;
        u16* xh  = (u16*)(ws + XH_OFF);
        u16* xl  = (u16*)(ws + XL_OFF);
        u16* xT  = (u16*)(ws + XT_OFF);
        u16* wtp = (u16*)(ws + WTP_OFF);
        u16* mth = (u16*)(ws + MTH_OFF);
        u16* mtl = (u16*)(ws + MTL_OFF);
        u16* y   = (u16*)(ws + Y_OFF);

        prep_all<<<5376, 512, 0, stream>>>(x, Muu, Mdd, Mud, Mdu,
                                           Auu, Add, Aud, Adu,
                                           xh, xl, xT, wtp, mth, mtl);
        attn_mfma<<<dim3(8, 16, 4), 256, 0, stream>>>(xh, xl, xT, wtp, mth, mtl, y);
        reduce_y<<<96, 512, 0, stream>>>(y, outp);
    } else {
        (void)hipMemsetAsync(d_out, 0, (size_t)out_size * sizeof(float), stream);
        attn_fused_fb<<<dim3(32, 16, 4), 256, 0, stream>>>(x, Muu, Mdd, Mud, Mdu,
                                                           Auu, Add, Aud, Adu, outp);
    }
}

// Round 15
// 132.896 us; speedup vs baseline: 1.2855x; 1.1621x over previous
//
#include <hip/hip_runtime.h>
#include <hip/hip_bf16.h>

typedef unsigned short u16;
typedef unsigned int   u32;
typedef _Float16 f16x8 __attribute__((ext_vector_type(8)));
typedef float    f32x16 __attribute__((ext_vector_type(16)));

#define HEADS 16
#define D     192
#define NUP   1024

// ---- workspace layout (bytes) ----
#define XB       (2048ull*192*2)               // 786432
#define XH_OFF   0ull
#define XL_OFF   (XH_OFF + XB)
#define XT_OFF   (XL_OFF + XB)
#define WM_BYTES (64ull*192*192*2)             // 4718592
#define WTP_OFF  (XT_OFF + XB)
#define MTH_OFF  (WTP_OFF + WM_BYTES)
#define MTL_OFF  (MTH_OFF + WM_BYTES)
#define Y_BYTES  (64ull*1024*192*2)            // 25165824 (fp16)
#define Y_OFF    (MTH_OFF + 2*WM_BYTES)
#define WS_NEED  (Y_OFF + Y_BYTES)             // 41680896

__device__ __forceinline__ u16 f2h(float v) {
    _Float16 h = (_Float16)v;
    return __builtin_bit_cast(u16, h);
}
__device__ __forceinline__ float h2f(u16 v) {
    return (float)__builtin_bit_cast(_Float16, v);
}
__device__ __forceinline__ u32 pk2h(float a, float b) {      // RNE
    return (u32)f2h(a) | ((u32)f2h(b) << 16);
}
__device__ __forceinline__ u32 pk2h_rtz(float a, float b) {  // 1-instr packed
    auto r = __builtin_amdgcn_cvt_pkrtz(a, b);
    return __builtin_bit_cast(u32, r);
}
// async global->LDS, 16B per lane (m97). LDS dest must be lane-linear.
__device__ __forceinline__ void gl_lds16(const u16* g, u16* l) {
    __builtin_amdgcn_global_load_lds(
        (const __attribute__((address_space(1))) void*)g,
        (__attribute__((address_space(3))) void*)l, 16, 0, 0);
}

// =====================================================================
// helper: assemble B-fragment (32x32x16) from 4 packed-pair u32s in
// D-frag order (m = (r&3)+8*(r>>2)+4*(lane>>5)) via half-swap (shfl —
// HW-verified R2..R12)
// =====================================================================
__device__ __forceinline__ f16x8 make_bfrag(u32 q0, u32 q1, u32 q2, u32 q3, bool hi) {
    u32 s0 = (u32)__shfl_xor((int)q0, 32);
    u32 s1 = (u32)__shfl_xor((int)q1, 32);
    u32 s2 = (u32)__shfl_xor((int)q2, 32);
    u32 s3 = (u32)__shfl_xor((int)q3, 32);
    uint4 w;
    w.x = hi ? s2 : q0;  w.y = hi ? s3 : q1;
    w.z = hi ? q2 : s0;  w.w = hi ? q3 : s1;
    return __builtin_bit_cast(f16x8, w);
}

// =====================================================================
// Prep ALL (merged): blocks [0,768) do x->xh,xl,xT ; rest build WT/MT.
// =====================================================================
__global__ __launch_bounds__(512)
void prep_all(const float* __restrict__ x,
              const float* __restrict__ Muu, const float* __restrict__ Mdd,
              const float* __restrict__ Mud, const float* __restrict__ Mdu,
              const float* __restrict__ Auu, const float* __restrict__ Add,
              const float* __restrict__ Aud, const float* __restrict__ Adu,
              u16* __restrict__ xh, u16* __restrict__ xl, u16* __restrict__ xT,
              u16* __restrict__ wtp, u16* __restrict__ mth, u16* __restrict__ mtl)
{
    int b = blockIdx.x;
    if (b < 768) {
        int i = b*512 + threadIdx.x;           // < 2048*192
        float v = x[i];
        int n = i / D, d = i - n*D;
        u16 hi = f2h(v);
        xh[i] = hi;
        xl[i] = f2h(v - h2f(hi));
        xT[(size_t)(n >> 5)*6144 + d*32 + (n & 31)] = hi;
        return;
    }
    int idx = (b - 768)*512 + threadIdx.x;     // < 64*36864
    int th = idx / 36864, r = idx - th*36864;
    int dout = r / 192, din = r - dout*192;
    int t = th >> 4, h = th & 15;
    const float* Ap = (t==0)?Auu:(t==1)?Aud:(t==2)?Add:Adu;
    const float* Mp = (t==0)?Muu:(t==1)?Mud:(t==2)?Mdd:Mdu;
    int g = dout / 6, zc = dout - g*6, z = zc >> 1, b0 = zc & 1;
    int f = din / 6,  zb = din - f*6,  z2 = zb >> 1, b1 = zb & 1;

    float wv = 0.0f, mv = 0.0f;
    if (z2 == z) {
        const float* a = Ap + (((size_t)h*32 + g)*32 + f)*6 + z*2;
        float A0 = a[0], A1 = a[1];
        wv = (b0 == 0) ? (b1 == 0 ? A0 : -A1) : (b1 == 0 ? A1 : A0);
        const float* m = Mp + (((size_t)h*32 + f)*32 + g)*6 + z*2;
        float M0 = m[0], M1 = m[1];
        mv = (b0 == 0) ? (b1 == 0 ? M0 : -M1) : (b1 == 0 ? M1 : M0);
    }
    int ob = dout >> 5, l31 = dout & 31;
    int ks = din >> 4, kr = din & 15, g32 = kr >> 3, j = kr & 7;
    size_t pidx = ((((size_t)th*6 + ob)*12 + ks)*64 + g32*32 + l31)*8 + j;
    wtp[pidx] = f2h(wv);
    u16 mh = f2h(mv);
    mth[pidx] = mh;
    mtl[pidx] = f2h(mv - h2f(mh));
}

// =====================================================================
// Main fused kernel — 4 waves x 32 q-rows = 128 rows, 256 threads,
// grid (8,16,4) = 512 blocks = 2 blocks/CU (m114 cross-block overlap).
// LDS: sXh[2] padded (25.6K) + sXT[2] UNPADDED lane-linear (24.6K).
// xh staged via regs (ld[3], no spill); xT staged via global_load_lds
// (zero VGPRs). PV reads LDS (low latency). Two barriers/iter; the
// staging barrier's drain is covered by the co-resident block.
// =====================================================================
__global__ __launch_bounds__(256, 2)
void attn_mfma(const u16* __restrict__ xh_g,  const u16* __restrict__ xl_g,
               const u16* __restrict__ xT_g,  const u16* __restrict__ wtp_g,
               const u16* __restrict__ mth_g, const u16* __restrict__ mtl_g,
               u16* __restrict__ y_g)
{
    const int nt = blockIdx.x, h = blockIdx.y, t = blockIdx.z;
    const int tid  = threadIdx.x;
    const int lane = tid & 63;
    const int l31  = lane & 31;
    const int g32  = lane >> 5;
    const int th   = t*16 + h;
    const int n0   = nt*128 + (tid >> 6)*32;
    const int qoff = (t <= 1) ? 0 : NUP;             // q-side rows
    const int koff = (t == 1 || t == 2) ? NUP : 0;   // k/v-side rows
    const int mtb  = koff >> 5;

    __shared__ u16 sXh[2][32*200];
    __shared__ u16 sXT[2][192*32];

    // ---- prologue: QM B-fragments via MFMA (3-term fp16 split) ----
    f16x8 qh[12];
    {
        f16x8 bxh[12], bxl[12];
        const u16* xrh = xh_g + (size_t)(qoff + n0 + l31)*D;
        const u16* xrl = xl_g + (size_t)(qoff + n0 + l31)*D;
        #pragma unroll
        for (int ks = 0; ks < 12; ++ks) {
            bxh[ks] = *reinterpret_cast<const f16x8*>(xrh + ks*16 + g32*8);
            bxl[ks] = *reinterpret_cast<const f16x8*>(xrl + ks*16 + g32*8);
        }
        const u16* mthb = mth_g + (size_t)th*36864;
        const u16* mtlb = mtl_g + (size_t)th*36864;
        #pragma unroll
        for (int obp = 0; obp < 3; ++obp) {      // 2 obs in flight for ILP
            const int ob0 = obp*2, ob1 = obp*2 + 1;
            f32x16 a0, a1;
            #pragma unroll
            for (int i = 0; i < 16; ++i) { a0[i] = 0.0f; a1[i] = 0.0f; }
            #pragma unroll
            for (int ks = 0; ks < 12; ++ks) {
                size_t fo0 = (((size_t)ob0*12 + ks)*64 + lane)*8;
                size_t fo1 = (((size_t)ob1*12 + ks)*64 + lane)*8;
                f16x8 amh0 = *reinterpret_cast<const f16x8*>(mthb + fo0);
                f16x8 aml0 = *reinterpret_cast<const f16x8*>(mtlb + fo0);
                f16x8 amh1 = *reinterpret_cast<const f16x8*>(mthb + fo1);
                f16x8 aml1 = *reinterpret_cast<const f16x8*>(mtlb + fo1);
                a0 = __builtin_amdgcn_mfma_f32_32x32x16_f16(amh0, bxh[ks], a0, 0, 0, 0);
                a1 = __builtin_amdgcn_mfma_f32_32x32x16_f16(amh1, bxh[ks], a1, 0, 0, 0);
                a0 = __builtin_amdgcn_mfma_f32_32x32x16_f16(amh0, bxl[ks], a0, 0, 0, 0);
                a1 = __builtin_amdgcn_mfma_f32_32x32x16_f16(amh1, bxl[ks], a1, 0, 0, 0);
                a0 = __builtin_amdgcn_mfma_f32_32x32x16_f16(aml0, bxh[ks], a0, 0, 0, 0);
                a1 = __builtin_amdgcn_mfma_f32_32x32x16_f16(aml1, bxh[ks], a1, 0, 0, 0);
            }
            u32 h0[8], h1[8];
            #pragma unroll
            for (int j = 0; j < 8; ++j) {
                h0[j] = pk2h(a0[2*j], a0[2*j+1]);
                h1[j] = pk2h(a1[2*j], a1[2*j+1]);
            }
            qh[ob0*2+0] = make_bfrag(h0[0], h0[1], h0[2], h0[3], g32);
            qh[ob0*2+1] = make_bfrag(h0[4], h0[5], h0[6], h0[7], g32);
            qh[ob1*2+0] = make_bfrag(h1[0], h1[1], h1[2], h1[3], g32);
            qh[ob1*2+1] = make_bfrag(h1[4], h1[5], h1[6], h1[7], g32);
        }
    }

    f32x16 vt[6];
    #pragma unroll
    for (int ob = 0; ob < 6; ++ob)
        #pragma unroll
        for (int i = 0; i < 16; ++i) vt[ob][i] = 0.0f;

    float run_m = -3.0e38f, run_l = 0.0f;

    uint4 ld[3];
    auto load_xh = [&](int mt) {            // xh rows: 768 chunks of 16B
        const int krow0 = koff + mt*32;
        #pragma unroll
        for (int i = 0; i < 3; ++i) {
            int c = tid + i*256;
            int rr = c/24, cc = c - rr*24;
            ld[i] = *reinterpret_cast<const uint4*>(
                xh_g + (size_t)(krow0 + rr)*D + cc*8);
        }
    };
    auto store_xh = [&](int xb) {
        #pragma unroll
        for (int i = 0; i < 3; ++i) {
            int c = tid + i*256;
            int rr = c/24, cc = c - rr*24;
            *reinterpret_cast<uint4*>(&sXh[xb][rr*200 + cc*8]) = ld[i];
        }
    };
    auto stage_xt = [&](int mt, int xb) {   // async, lane-linear, 0 VGPRs
        const u16* gsrc = xT_g + (size_t)(mtb + mt)*6144;
        #pragma unroll
        for (int i = 0; i < 3; ++i) {
            int c = tid + i*256;            // chunk id; byte off = c*16
            gl_lds16(gsrc + c*8, &sXT[xb][c*8]);
        }
    };
    auto SCORES = [&](int xb, f32x16 &sOut) {
        f32x16 s0, s1;
        #pragma unroll
        for (int i = 0; i < 16; ++i) { s0[i] = 0.0f; s1[i] = 0.0f; }
        __builtin_amdgcn_s_setprio(1);
        #pragma unroll
        for (int ks = 0; ks < 6; ++ks) {
            f16x8 ah0 = *reinterpret_cast<const f16x8*>(&sXh[xb][l31*200 + ks*16 + g32*8]);
            f16x8 ah1 = *reinterpret_cast<const f16x8*>(&sXh[xb][l31*200 + (ks+6)*16 + g32*8]);
            s0 = __builtin_amdgcn_mfma_f32_32x32x16_f16(ah0, qh[ks],   s0, 0, 0, 0);
            s1 = __builtin_amdgcn_mfma_f32_32x32x16_f16(ah1, qh[ks+6], s1, 0, 0, 0);
        }
        __builtin_amdgcn_s_setprio(0);
        #pragma unroll
        for (int i = 0; i < 16; ++i) sOut[i] = s0[i] + s1[i];
    };
    auto SOFTMAX = [&](f32x16 &sIn, f16x8 &pf0, f16x8 &pf1) {
        float tmax = sIn[0];
        #pragma unroll
        for (int i = 1; i < 16; ++i) tmax = fmaxf(tmax, sIn[i]);
        tmax = fmaxf(tmax, __shfl_xor(tmax, 32));
        if (__any(tmax > run_m + 8.0f)) {       // defer-rescale (T13)
            float nm = fmaxf(run_m, tmax);
            float rs = __expf(run_m - nm);
            #pragma unroll
            for (int ob = 0; ob < 6; ++ob)
                #pragma unroll
                for (int i = 0; i < 16; ++i) vt[ob][i] *= rs;
            run_l *= rs;
            run_m = nm;
        }
        float psum = 0.0f;
        u32 q[8];
        #pragma unroll
        for (int j = 0; j < 8; ++j) {
            float p0 = __expf(sIn[2*j]   - run_m);
            float p1 = __expf(sIn[2*j+1] - run_m);
            psum += p0 + p1;
            q[j] = pk2h_rtz(p0, p1);
        }
        psum += __shfl_xor(psum, 32);
        run_l += psum;
        pf0 = make_bfrag(q[0], q[1], q[2], q[3], g32);
        pf1 = make_bfrag(q[4], q[5], q[6], q[7], g32);
    };
    auto PV = [&](int bp, f16x8 pf0, f16x8 pf1) {   // unpadded stride 32
        __builtin_amdgcn_s_setprio(1);
        #pragma unroll
        for (int ob = 0; ob < 6; ++ob) {
            f16x8 a0 = *reinterpret_cast<const f16x8*>(&sXT[bp][(ob*32 + l31)*32 + g32*8]);
            f16x8 a1 = *reinterpret_cast<const f16x8*>(&sXT[bp][(ob*32 + l31)*32 + 16 + g32*8]);
            vt[ob] = __builtin_amdgcn_mfma_f32_32x32x16_f16(a0, pf0, vt[ob], 0, 0, 0);
            vt[ob] = __builtin_amdgcn_mfma_f32_32x32x16_f16(a1, pf1, vt[ob], 0, 0, 0);
        }
        __builtin_amdgcn_s_setprio(0);
    };

    f32x16 sA, sB;

    // ---- pipeline prologue ----
    load_xh(0); store_xh(0); stage_xt(0, 0);
    __syncthreads();                       // vmcnt drain: tile0 staged
    load_xh(1);
    SCORES(0, sA);                         // scores(0) from sXh[0]
    store_xh(1); stage_xt(1, 1);           // idle buffers, no race
    __syncthreads();

    // STEP(cur): SCORES(cur); softmax+PV(cur-1); then stage tile cur+1
    auto STEP = [&](int cur, f32x16 &sCur, f32x16 &sPrev) {
        if (cur < 31) load_xh(cur + 1);
        SCORES(cur & 1, sCur);               // MFMA(cur) issues...
        f16x8 pf0, pf1;
        SOFTMAX(sPrev, pf0, pf1);            // ...while VALU does softmax(prev)
        PV((cur - 1) & 1, pf0, pf1);
        __syncthreads();                     // readers of (cur+1)&1 bufs done
        if (cur < 31) {
            store_xh((cur + 1) & 1);
            stage_xt(cur + 1, (cur + 1) & 1);
            __syncthreads();                 // staging visible (vmcnt drain)
        }
    };

    #pragma unroll 1
    for (int m2 = 1; m2 <= 29; m2 += 2) {
        STEP(m2,     sB, sA);
        STEP(m2 + 1, sA, sB);
    }
    STEP(31, sB, sA);                        // scores(31), softmax+PV(30)
    // ---- epilogue: softmax + PV of tile31 (in sXT[1]) ----
    {
        f16x8 pf0, pf1;
        SOFTMAX(sB, pf0, pf1);
        PV(1, pf0, pf1);
    }

    // --- normalize ---
    float inv = 1.0f / run_l;
    #pragma unroll
    for (int ob = 0; ob < 6; ++ob)
        #pragma unroll
        for (int i = 0; i < 16; ++i) vt[ob][i] *= inv;

    // --- combine: Y^T[dout][n] = sum_din WT[dout][din] * Vt^T[din][n] ---
    const u16* wbase = wtp_g + (size_t)th*36864;
    f32x16 y[6];
    #pragma unroll
    for (int ob = 0; ob < 6; ++ob)
        #pragma unroll
        for (int i = 0; i < 16; ++i) y[ob][i] = 0.0f;

    #pragma unroll
    for (int ob = 0; ob < 6; ++ob) {
        u32 qq[8];
        #pragma unroll
        for (int j = 0; j < 8; ++j) qq[j] = pk2h_rtz(vt[ob][2*j], vt[ob][2*j+1]);
        #pragma unroll
        for (int half = 0; half < 2; ++half) {
            int ks = ob*2 + half;
            f16x8 bfr = half ? make_bfrag(qq[4], qq[5], qq[6], qq[7], g32)
                             : make_bfrag(qq[0], qq[1], qq[2], qq[3], g32);
            #pragma unroll
            for (int ob2 = 0; ob2 < 6; ++ob2) {
                f16x8 a = *reinterpret_cast<const f16x8*>(
                    wbase + ((((size_t)ob2*12) + ks)*64 + lane)*8);
                y[ob2] = __builtin_amdgcn_mfma_f32_32x32x16_f16(a, bfr, y[ob2], 0, 0, 0);
            }
        }
    }

    // --- write partial Y[t][h][n][dout] (fp16) ---
    u16* yrow = y_g + ((size_t)th*1024 + n0 + l31)*D;
    #pragma unroll
    for (int ob = 0; ob < 6; ++ob)
        #pragma unroll
        for (int rq = 0; rq < 4; ++rq) {
            uint2 v;
            v.x = pk2h_rtz(y[ob][rq*4+0], y[ob][rq*4+1]);
            v.y = pk2h_rtz(y[ob][rq*4+2], y[ob][rq*4+3]);
            *reinterpret_cast<uint2*>(yrow + ob*32 + rq*8 + g32*4) = v;
        }
}

// =====================================================================
// Reduce: out[p*1024+n][d] = sum_{t in pair, h} y[t][h][n][d]  (fp16 in)
// =====================================================================
__global__ __launch_bounds__(512)
void reduce_y(const u16* __restrict__ y_g, float* __restrict__ out)
{
    int gi = blockIdx.x*512 + threadIdx.x;     // < 2048*192/8
    int n = gi / 24, c = gi - n*24;
    int p = n >> 10, nn = n & 1023;
    float acc[8];
    #pragma unroll
    for (int j = 0; j < 8; ++j) acc[j] = 0.0f;
    #pragma unroll
    for (int k = 0; k < 32; ++k) {
        int tcur = p*2 + (k >> 4), hh = k & 15;
        uint4 v = *reinterpret_cast<const uint4*>(
            y_g + ((size_t)((tcur*16+hh)*1024 + nn))*D + c*8);
        u32 w[4] = {v.x, v.y, v.z, v.w};
        #pragma unroll
        for (int j = 0; j < 4; ++j) {
            acc[2*j]   += h2f((u16)(w[j] & 0xffffu));
            acc[2*j+1] += h2f((u16)(w[j] >> 16));
        }
    }
    float* op = out + (size_t)n*D + c*8;
    float4 o0 = {acc[0], acc[1], acc[2], acc[3]};
    float4 o1 = {acc[4], acc[5], acc[6], acc[7]};
    *reinterpret_cast<float4*>(op)     = o0;
    *reinterpret_cast<float4*>(op + 4) = o1;
}

// =====================================================================
// Fallback (round-1 fp32 kernel) if ws too small
// =====================================================================
__global__ __launch_bounds__(256, 2)
void attn_fused_fb(const float* __restrict__ x,
                const float* __restrict__ Muu, const float* __restrict__ Mdd,
                const float* __restrict__ Mud, const float* __restrict__ Mdu,
                const float* __restrict__ Auu, const float* __restrict__ Add,
                const float* __restrict__ Aud, const float* __restrict__ Adu,
                float* __restrict__ out)
{
    const int nt  = blockIdx.x;
    const int h   = blockIdx.y;
    const int t   = blockIdx.z;
    const int tid = threadIdx.x;
    const float* qb = (t <= 1) ? x : x + (size_t)NUP*D;
    const float* kb = (t == 0 || t == 3) ? x : x + (size_t)NUP*D;
    const float* Mp = (t==0)?Muu:(t==1)?Mud:(t==2)?Mdd:Mdu;
    const float* Ap = (t==0)?Auu:(t==1)?Aud:(t==2)?Add:Adu;
    const float* Mh = Mp + (size_t)h*32*D;
    const float* Ah = Ap + (size_t)h*32*D;
    float* ob = out + ((t>=2) ? (size_t)NUP*D : 0);

    __shared__ float sK[32*196];
    __shared__ float sQM[32*196];
    __shared__ float sS[32*33];
    __shared__ float sTmp[32*8];
    __shared__ float sR[32];
    __shared__ float sMaxRun[32];
    __shared__ float sSumRun[32];

    if (tid < 32) { sMaxRun[tid] = -3.0e38f; sSumRun[tid] = 0.0f; }
    for (int i = tid; i < 32*D/4; i += 256)
        reinterpret_cast<float4*>(sK)[i] = reinterpret_cast<const float4*>(Mh)[i];
    __syncthreads();

    #pragma unroll
    for (int kk = 0; kk < 4; ++kk) {
        int p = tid + kk*256;
        int n = p >> 5, g = p & 31;
        const float* qrow = qb + (size_t)(nt*32 + n)*D;
        float acc[6] = {0,0,0,0,0,0};
        for (int f = 0; f < 32; ++f) {
            const float* qf = qrow + f*6;
            const float* mf = sK + f*D + g*6;
            #pragma unroll
            for (int z = 0; z < 3; ++z) {
                float q0 = qf[2*z], q1 = qf[2*z+1];
                float m0 = mf[2*z], m1 = mf[2*z+1];
                acc[2*z]   += q0*m0 - q1*m1;
                acc[2*z+1] += q1*m0 + q0*m1;
            }
        }
        #pragma unroll
        for (int j = 0; j < 6; ++j) sQM[n*196 + g*6 + j] = acc[j];
    }

    const int gn = tid >> 5;
    const int cg = tid & 31;
    const int cbase = cg*6;
    float vacc[4][6];
    #pragma unroll
    for (int a = 0; a < 4; ++a)
        #pragma unroll
        for (int b = 0; b < 6; ++b) vacc[a][b] = 0.0f;

    const int txm = tid & 15, tyn = tid >> 4;

    for (int mt = 0; mt < 32; ++mt) {
        __syncthreads();
        for (int i = tid; i < 32*(D/4); i += 256) {
            int row = i / (D/4), j = i - row*(D/4);
            float4 v = reinterpret_cast<const float4*>(kb + (size_t)(mt*32 + row)*D)[j];
            *reinterpret_cast<float4*>(&sK[row*196 + j*4]) = v;
        }
        __syncthreads();

        float a00=0,a01=0,a10=0,a11=0;
        {
            const float* q0p = &sQM[tyn*196];
            const float* q1p = &sQM[(tyn+16)*196];
            const float* k0p = &sK[txm*196];
            const float* k1p = &sK[(txm+16)*196];
            for (int k = 0; k < D; k += 4) {
                float4 qa = *reinterpret_cast<const float4*>(q0p+k);
                float4 qc = *reinterpret_cast<const float4*>(q1p+k);
                float4 ka = *reinterpret_cast<const float4*>(k0p+k);
                float4 kc = *reinterpret_cast<const float4*>(k1p+k);
                a00 += qa.x*ka.x + qa.y*ka.y + qa.z*ka.z + qa.w*ka.w;
                a01 += qa.x*kc.x + qa.y*kc.y + qa.z*kc.z + qa.w*kc.w;
                a10 += qc.x*ka.x + qc.y*ka.y + qc.z*ka.z + qc.w*ka.w;
                a11 += qc.x*kc.x + qc.y*kc.y + qc.z*kc.z + qc.w*kc.w;
            }
        }
        sS[tyn*33 + txm]          = a00;
        sS[tyn*33 + txm+16]       = a01;
        sS[(tyn+16)*33 + txm]     = a10;
        sS[(tyn+16)*33 + txm+16]  = a11;
        __syncthreads();

        const int srow = tid >> 3, sj = tid & 7;
        {
            const float* r = &sS[srow*33];
            float mx = fmaxf(fmaxf(r[sj], r[sj+8]), fmaxf(r[sj+16], r[sj+24]));
            sTmp[srow*8 + sj] = mx;
        }
        __syncthreads();
        if (tid < 32) {
            float mx = sTmp[tid*8];
            #pragma unroll
            for (int j = 1; j < 8; ++j) mx = fmaxf(mx, sTmp[tid*8+j]);
            float om = sMaxRun[tid];
            float nm = fmaxf(om, mx);
            sR[tid] = __expf(om - nm);
            sMaxRun[tid] = nm;
        }
        __syncthreads();
        {
            float nm = sMaxRun[srow];
            float* r = &sS[srow*33];
            float p0 = __expf(r[sj]    - nm);
            float p1 = __expf(r[sj+8]  - nm);
            float p2 = __expf(r[sj+16] - nm);
            float p3 = __expf(r[sj+24] - nm);
            r[sj] = p0; r[sj+8] = p1; r[sj+16] = p2; r[sj+24] = p3;
            sTmp[srow*8+sj] = p0+p1+p2+p3;
        }
        __syncthreads();
        if (tid < 32) {
            float s = 0.0f;
            #pragma unroll
            for (int j = 0; j < 8; ++j) s += sTmp[tid*8+j];
            sSumRun[tid] = sSumRun[tid]*sR[tid] + s;
        }
        {
            float r0 = sR[gn*4+0], r1 = sR[gn*4+1], r2 = sR[gn*4+2], r3 = sR[gn*4+3];
            #pragma unroll
            for (int b = 0; b < 6; ++b) { vacc[0][b]*=r0; vacc[1][b]*=r1; vacc[2][b]*=r2; vacc[3][b]*=r3; }
            for (int m = 0; m < 32; ++m) {
                float p0 = sS[(gn*4+0)*33+m];
                float p1 = sS[(gn*4+1)*33+m];
                float p2 = sS[(gn*4+2)*33+m];
                float p3 = sS[(gn*4+3)*33+m];
                const float* kr = &sK[m*196 + cbase];
                #pragma unroll
                for (int b = 0; b < 6; ++b) {
                    float kv = kr[b];
                    vacc[0][b] += p0*kv;
                    vacc[1][b] += p1*kv;
                    vacc[2][b] += p2*kv;
                    vacc[3][b] += p3*kv;
                }
            }
        }
    }

    __syncthreads();
    {
        float i0 = 1.0f/sSumRun[gn*4+0], i1 = 1.0f/sSumRun[gn*4+1];
        float i2 = 1.0f/sSumRun[gn*4+2], i3 = 1.0f/sSumRun[gn*4+3];
        #pragma unroll
        for (int b = 0; b < 6; ++b) {
            sQM[(gn*4+0)*196 + cbase + b] = vacc[0][b]*i0;
            sQM[(gn*4+1)*196 + cbase + b] = vacc[1][b]*i1;
            sQM[(gn*4+2)*196 + cbase + b] = vacc[2][b]*i2;
            sQM[(gn*4+3)*196 + cbase + b] = vacc[3][b]*i3;
        }
    }
    for (int i = tid; i < 32*D/4; i += 256)
        reinterpret_cast<float4*>(sK)[i] = reinterpret_cast<const float4*>(Ah)[i];
    __syncthreads();

    #pragma unroll
    for (int kk = 0; kk < 4; ++kk) {
        int p = tid + kk*256;
        int n = p >> 5, g = p & 31;
        float acc[6] = {0,0,0,0,0,0};
        const float* vb = &sQM[n*196];
        const float* ab = &sK[g*D];
        for (int f = 0; f < 32; ++f) {
            const float* vf = vb + f*6;
            const float* af = ab + f*6;
            #pragma unroll
            for (int z = 0; z < 3; ++z) {
                float V0 = vf[2*z], V1 = vf[2*z+1];
                float A0 = af[2*z], A1 = af[2*z+1];
                acc[2*z]   += A0*V0 - A1*V1;
                acc[2*z+1] += A0*V1 + A1*V0;
            }
        }
        float* op = ob + (size_t)(nt*32 + n)*D + g*6;
        #pragma unroll
        for (int j = 0; j < 6; ++j) atomicAdd(op + j, acc[j]);
    }
}

extern "C" void kernel_launch(void* const* d_in, const int* in_sizes, int n_in,
                              void* d_out, int out_size, void* d_ws, size_t ws_size,
                              hipStream_t stream) {
    const float* x   = (const float*)d_in[0];
    const float* Muu = (const float*)d_in[1];
    const float* Mdd = (const float*)d_in[2];
    const float* Mud = (const float*)d_in[3];
    const float* Mdu = (const float*)d_in[4];
    const float* Auu = (const float*)d_in[5];
    const float* Add = (const float*)d_in[6];
    const float* Aud = (const float*)d_in[7];
    const float* Adu = (const float*)d_in[8];
    float* outp = (float*)d_out;

    if (ws_size >= WS_NEED) {
        char* ws = (char*)d_ws;
        u16* xh  = (u16*)(ws + XH_OFF);
        u16* xl  = (u16*)(ws + XL_OFF);
        u16* xT  = (u16*)(ws + XT_OFF);
        u16* wtp = (u16*)(ws + WTP_OFF);
        u16* mth = (u16*)(ws + MTH_OFF);
        u16* mtl = (u16*)(ws + MTL_OFF);
        u16* y   = (u16*)(ws + Y_OFF);

        prep_all<<<5376, 512, 0, stream>>>(x, Muu, Mdd, Mud, Mdu,
                                           Auu, Add, Aud, Adu,
                                           xh, xl, xT, wtp, mth, mtl);
        attn_mfma<<<dim3(8, 16, 4), 256, 0, stream>>>(xh, xl, xT, wtp, mth, mtl, y);
        reduce_y<<<96, 512, 0, stream>>>(y, outp);
    } else {
        (void)hipMemsetAsync(d_out, 0, (size_t)out_size * sizeof(float), stream);
        attn_fused_fb<<<dim3(32, 16, 4), 256, 0, stream>>>(x, Muu, Mdd, Mud, Mdu,
                                                           Auu, Add, Aud, Adu, outp);
    }
}

// Round 16
// 130.270 us; speedup vs baseline: 1.3115x; 1.0202x over previous
//
#include <hip/hip_runtime.h>
#include <hip/hip_bf16.h>

typedef unsigned short u16;
typedef unsigned int   u32;
typedef _Float16 f16x8 __attribute__((ext_vector_type(8)));
typedef float    f32x16 __attribute__((ext_vector_type(16)));

#define HEADS 16
#define D     192
#define NUP   1024

// ---- workspace layout (bytes) ----
#define XB       (2048ull*192*2)               // 786432
#define XH_OFF   0ull
#define XL_OFF   (XH_OFF + XB)
#define XT_OFF   (XL_OFF + XB)
#define WM_BYTES (64ull*192*192*2)             // 4718592
#define WTP_OFF  (XT_OFF + XB)
#define MTH_OFF  (WTP_OFF + WM_BYTES)
#define MTL_OFF  (MTH_OFF + WM_BYTES)
#define Y_BYTES  (64ull*1024*192*2)            // 25165824 (fp16)
#define Y_OFF    (MTH_OFF + 2*WM_BYTES)
#define WS_NEED  (Y_OFF + Y_BYTES)             // 41680896

__device__ __forceinline__ u16 f2h(float v) {
    _Float16 h = (_Float16)v;
    return __builtin_bit_cast(u16, h);
}
__device__ __forceinline__ float h2f(u16 v) {
    return (float)__builtin_bit_cast(_Float16, v);
}
__device__ __forceinline__ u32 pk2h(float a, float b) {      // RNE
    return (u32)f2h(a) | ((u32)f2h(b) << 16);
}
__device__ __forceinline__ u32 pk2h_rtz(float a, float b) {  // 1-instr packed
    auto r = __builtin_amdgcn_cvt_pkrtz(a, b);
    return __builtin_bit_cast(u32, r);
}
// async global->LDS, 16B per lane (m97). LDS dest must be lane-linear.
__device__ __forceinline__ void gl_lds16(const u16* g, u16* l) {
    __builtin_amdgcn_global_load_lds(
        (const __attribute__((address_space(1))) void*)g,
        (__attribute__((address_space(3))) void*)l, 16, 0, 0);
}

// =====================================================================
// helper: assemble B-fragment (32x32x16) from 4 packed-pair u32s in
// D-frag order (m = (r&3)+8*(r>>2)+4*(lane>>5)) via half-swap (shfl —
// HW-verified R2..R12)
// =====================================================================
__device__ __forceinline__ f16x8 make_bfrag(u32 q0, u32 q1, u32 q2, u32 q3, bool hi) {
    u32 s0 = (u32)__shfl_xor((int)q0, 32);
    u32 s1 = (u32)__shfl_xor((int)q1, 32);
    u32 s2 = (u32)__shfl_xor((int)q2, 32);
    u32 s3 = (u32)__shfl_xor((int)q3, 32);
    uint4 w;
    w.x = hi ? s2 : q0;  w.y = hi ? s3 : q1;
    w.z = hi ? q2 : s0;  w.w = hi ? q3 : s1;
    return __builtin_bit_cast(f16x8, w);
}

// =====================================================================
// Prep ALL (merged): blocks [0,768) do x->xh,xl,xT ; rest build WT/MT.
// xT stored XOR-swizzled (T2/m173): elem (d, n32) at
//   tile*6144 + d*32 + ((n32>>3) ^ ((d>>1)&3))*8 + (n32&7)
// so the lane-linear global_load_lds write yields a bank-spread layout.
// =====================================================================
__global__ __launch_bounds__(512)
void prep_all(const float* __restrict__ x,
              const float* __restrict__ Muu, const float* __restrict__ Mdd,
              const float* __restrict__ Mud, const float* __restrict__ Mdu,
              const float* __restrict__ Auu, const float* __restrict__ Add,
              const float* __restrict__ Aud, const float* __restrict__ Adu,
              u16* __restrict__ xh, u16* __restrict__ xl, u16* __restrict__ xT,
              u16* __restrict__ wtp, u16* __restrict__ mth, u16* __restrict__ mtl)
{
    int b = blockIdx.x;
    if (b < 768) {
        int i = b*512 + threadIdx.x;           // < 2048*192
        float v = x[i];
        int n = i / D, d = i - n*D;
        u16 hi = f2h(v);
        xh[i] = hi;
        xl[i] = f2h(v - h2f(hi));
        int n32 = n & 31, q = n32 >> 3, sw = (d >> 1) & 3;
        xT[(size_t)(n >> 5)*6144 + d*32 + ((q ^ sw) << 3) + (n32 & 7)] = hi;
        return;
    }
    int idx = (b - 768)*512 + threadIdx.x;     // < 64*36864
    int th = idx / 36864, r = idx - th*36864;
    int dout = r / 192, din = r - dout*192;
    int t = th >> 4, h = th & 15;
    const float* Ap = (t==0)?Auu:(t==1)?Aud:(t==2)?Add:Adu;
    const float* Mp = (t==0)?Muu:(t==1)?Mud:(t==2)?Mdd:Mdu;
    int g = dout / 6, zc = dout - g*6, z = zc >> 1, b0 = zc & 1;
    int f = din / 6,  zb = din - f*6,  z2 = zb >> 1, b1 = zb & 1;

    float wv = 0.0f, mv = 0.0f;
    if (z2 == z) {
        const float* a = Ap + (((size_t)h*32 + g)*32 + f)*6 + z*2;
        float A0 = a[0], A1 = a[1];
        wv = (b0 == 0) ? (b1 == 0 ? A0 : -A1) : (b1 == 0 ? A1 : A0);
        const float* m = Mp + (((size_t)h*32 + f)*32 + g)*6 + z*2;
        float M0 = m[0], M1 = m[1];
        mv = (b0 == 0) ? (b1 == 0 ? M0 : -M1) : (b1 == 0 ? M1 : M0);
    }
    int ob = dout >> 5, l31 = dout & 31;
    int ks = din >> 4, kr = din & 15, g32 = kr >> 3, j = kr & 7;
    size_t pidx = ((((size_t)th*6 + ob)*12 + ks)*64 + g32*32 + l31)*8 + j;
    wtp[pidx] = f2h(wv);
    u16 mh = f2h(mv);
    mth[pidx] = mh;
    mtl[pidx] = f2h(mv - h2f(mh));
}

// =====================================================================
// Main fused kernel — 4 waves x 32 q-rows = 128 rows, 256 threads,
// grid (8,16,4) = 512 blocks = 2 blocks/CU (m114 cross-block overlap).
// LDS: sXh[2] padded (25.6K) + sXT[2] swizzled lane-linear (24.6K).
// xh staged via regs; xT via global_load_lds (0 VGPRs, pre-swizzled
// source -> conflict-free PV reads). Two barriers/iter.
// =====================================================================
__global__ __launch_bounds__(256, 2)
void attn_mfma(const u16* __restrict__ xh_g,  const u16* __restrict__ xl_g,
               const u16* __restrict__ xT_g,  const u16* __restrict__ wtp_g,
               const u16* __restrict__ mth_g, const u16* __restrict__ mtl_g,
               u16* __restrict__ y_g)
{
    const int nt = blockIdx.x, h = blockIdx.y, t = blockIdx.z;
    const int tid  = threadIdx.x;
    const int lane = tid & 63;
    const int l31  = lane & 31;
    const int g32  = lane >> 5;
    const int th   = t*16 + h;
    const int n0   = nt*128 + (tid >> 6)*32;
    const int qoff = (t <= 1) ? 0 : NUP;             // q-side rows
    const int koff = (t == 1 || t == 2) ? NUP : 0;   // k/v-side rows
    const int mtb  = koff >> 5;
    const int swz  = (l31 >> 1) & 3;                 // xT swizzle (ob-indep)

    __shared__ u16 sXh[2][32*200];
    __shared__ u16 sXT[2][192*32];

    // ---- prologue: QM B-fragments via MFMA (3-term fp16 split) ----
    f16x8 qh[12];
    {
        f16x8 bxh[12], bxl[12];
        const u16* xrh = xh_g + (size_t)(qoff + n0 + l31)*D;
        const u16* xrl = xl_g + (size_t)(qoff + n0 + l31)*D;
        #pragma unroll
        for (int ks = 0; ks < 12; ++ks) {
            bxh[ks] = *reinterpret_cast<const f16x8*>(xrh + ks*16 + g32*8);
            bxl[ks] = *reinterpret_cast<const f16x8*>(xrl + ks*16 + g32*8);
        }
        const u16* mthb = mth_g + (size_t)th*36864;
        const u16* mtlb = mtl_g + (size_t)th*36864;
        #pragma unroll
        for (int obp = 0; obp < 3; ++obp) {      // 2 obs in flight for ILP
            const int ob0 = obp*2, ob1 = obp*2 + 1;
            f32x16 a0, a1;
            #pragma unroll
            for (int i = 0; i < 16; ++i) { a0[i] = 0.0f; a1[i] = 0.0f; }
            #pragma unroll
            for (int ks = 0; ks < 12; ++ks) {
                size_t fo0 = (((size_t)ob0*12 + ks)*64 + lane)*8;
                size_t fo1 = (((size_t)ob1*12 + ks)*64 + lane)*8;
                f16x8 amh0 = *reinterpret_cast<const f16x8*>(mthb + fo0);
                f16x8 aml0 = *reinterpret_cast<const f16x8*>(mtlb + fo0);
                f16x8 amh1 = *reinterpret_cast<const f16x8*>(mthb + fo1);
                f16x8 aml1 = *reinterpret_cast<const f16x8*>(mtlb + fo1);
                a0 = __builtin_amdgcn_mfma_f32_32x32x16_f16(amh0, bxh[ks], a0, 0, 0, 0);
                a1 = __builtin_amdgcn_mfma_f32_32x32x16_f16(amh1, bxh[ks], a1, 0, 0, 0);
                a0 = __builtin_amdgcn_mfma_f32_32x32x16_f16(amh0, bxl[ks], a0, 0, 0, 0);
                a1 = __builtin_amdgcn_mfma_f32_32x32x16_f16(amh1, bxl[ks], a1, 0, 0, 0);
                a0 = __builtin_amdgcn_mfma_f32_32x32x16_f16(aml0, bxh[ks], a0, 0, 0, 0);
                a1 = __builtin_amdgcn_mfma_f32_32x32x16_f16(aml1, bxh[ks], a1, 0, 0, 0);
            }
            u32 h0[8], h1[8];
            #pragma unroll
            for (int j = 0; j < 8; ++j) {
                h0[j] = pk2h(a0[2*j], a0[2*j+1]);
                h1[j] = pk2h(a1[2*j], a1[2*j+1]);
            }
            qh[ob0*2+0] = make_bfrag(h0[0], h0[1], h0[2], h0[3], g32);
            qh[ob0*2+1] = make_bfrag(h0[4], h0[5], h0[6], h0[7], g32);
            qh[ob1*2+0] = make_bfrag(h1[0], h1[1], h1[2], h1[3], g32);
            qh[ob1*2+1] = make_bfrag(h1[4], h1[5], h1[6], h1[7], g32);
        }
    }

    f32x16 vt[6];
    #pragma unroll
    for (int ob = 0; ob < 6; ++ob)
        #pragma unroll
        for (int i = 0; i < 16; ++i) vt[ob][i] = 0.0f;

    float run_m = -3.0e38f, run_l = 0.0f;

    uint4 ld[3];
    auto load_xh = [&](int mt) {            // xh rows: 768 chunks of 16B
        const int krow0 = koff + mt*32;
        #pragma unroll
        for (int i = 0; i < 3; ++i) {
            int c = tid + i*256;
            int rr = c/24, cc = c - rr*24;
            ld[i] = *reinterpret_cast<const uint4*>(
                xh_g + (size_t)(krow0 + rr)*D + cc*8);
        }
    };
    auto store_xh = [&](int xb) {
        #pragma unroll
        for (int i = 0; i < 3; ++i) {
            int c = tid + i*256;
            int rr = c/24, cc = c - rr*24;
            *reinterpret_cast<uint4*>(&sXh[xb][rr*200 + cc*8]) = ld[i];
        }
    };
    auto stage_xt = [&](int mt, int xb) {   // async, lane-linear, 0 VGPRs
        const u16* gsrc = xT_g + (size_t)(mtb + mt)*6144;
        #pragma unroll
        for (int i = 0; i < 3; ++i) {
            int c = tid + i*256;            // chunk id; byte off = c*16
            gl_lds16(gsrc + c*8, &sXT[xb][c*8]);
        }
    };
    auto SCORES = [&](int xb, f32x16 &sOut) {
        f32x16 s0, s1;
        #pragma unroll
        for (int i = 0; i < 16; ++i) { s0[i] = 0.0f; s1[i] = 0.0f; }
        __builtin_amdgcn_s_setprio(1);
        #pragma unroll
        for (int ks = 0; ks < 6; ++ks) {
            f16x8 ah0 = *reinterpret_cast<const f16x8*>(&sXh[xb][l31*200 + ks*16 + g32*8]);
            f16x8 ah1 = *reinterpret_cast<const f16x8*>(&sXh[xb][l31*200 + (ks+6)*16 + g32*8]);
            s0 = __builtin_amdgcn_mfma_f32_32x32x16_f16(ah0, qh[ks],   s0, 0, 0, 0);
            s1 = __builtin_amdgcn_mfma_f32_32x32x16_f16(ah1, qh[ks+6], s1, 0, 0, 0);
        }
        __builtin_amdgcn_s_setprio(0);
        #pragma unroll
        for (int i = 0; i < 16; ++i) sOut[i] = s0[i] + s1[i];
    };
    auto SOFTMAX = [&](f32x16 &sIn, f16x8 &pf0, f16x8 &pf1) {
        float tmax = sIn[0];
        #pragma unroll
        for (int i = 1; i < 16; ++i) tmax = fmaxf(tmax, sIn[i]);
        tmax = fmaxf(tmax, __shfl_xor(tmax, 32));
        if (__any(tmax > run_m + 8.0f)) {       // defer-rescale (T13)
            float nm = fmaxf(run_m, tmax);
            float rs = __expf(run_m - nm);
            #pragma unroll
            for (int ob = 0; ob < 6; ++ob)
                #pragma unroll
                for (int i = 0; i < 16; ++i) vt[ob][i] *= rs;
            run_l *= rs;
            run_m = nm;
        }
        float psum = 0.0f;
        u32 q[8];
        #pragma unroll
        for (int j = 0; j < 8; ++j) {
            float p0 = __expf(sIn[2*j]   - run_m);
            float p1 = __expf(sIn[2*j+1] - run_m);
            psum += p0 + p1;
            q[j] = pk2h_rtz(p0, p1);
        }
        psum += __shfl_xor(psum, 32);
        run_l += psum;
        pf0 = make_bfrag(q[0], q[1], q[2], q[3], g32);
        pf1 = make_bfrag(q[4], q[5], q[6], q[7], g32);
    };
    auto PV = [&](int bp, f16x8 pf0, f16x8 pf1) {   // swizzled reads
        __builtin_amdgcn_s_setprio(1);
        #pragma unroll
        for (int ob = 0; ob < 6; ++ob) {
            int rb = (ob*32 + l31)*32;
            f16x8 a0 = *reinterpret_cast<const f16x8*>(&sXT[bp][rb + ((g32 ^ swz) << 3)]);
            f16x8 a1 = *reinterpret_cast<const f16x8*>(&sXT[bp][rb + (((2 + g32) ^ swz) << 3)]);
            vt[ob] = __builtin_amdgcn_mfma_f32_32x32x16_f16(a0, pf0, vt[ob], 0, 0, 0);
            vt[ob] = __builtin_amdgcn_mfma_f32_32x32x16_f16(a1, pf1, vt[ob], 0, 0, 0);
        }
        __builtin_amdgcn_s_setprio(0);
    };

    f32x16 sA, sB;

    // ---- pipeline prologue ----
    load_xh(0); store_xh(0); stage_xt(0, 0);
    __syncthreads();                       // vmcnt drain: tile0 staged
    load_xh(1);
    SCORES(0, sA);                         // scores(0) from sXh[0]
    store_xh(1); stage_xt(1, 1);           // idle buffers, no race
    __syncthreads();

    // STEP(cur): SCORES(cur); softmax+PV(cur-1); then stage tile cur+1
    auto STEP = [&](int cur, f32x16 &sCur, f32x16 &sPrev) {
        if (cur < 31) load_xh(cur + 1);
        SCORES(cur & 1, sCur);               // MFMA(cur) issues...
        f16x8 pf0, pf1;
        SOFTMAX(sPrev, pf0, pf1);            // ...while VALU does softmax(prev)
        PV((cur - 1) & 1, pf0, pf1);
        __syncthreads();                     // readers of (cur+1)&1 bufs done
        if (cur < 31) {
            store_xh((cur + 1) & 1);
            stage_xt(cur + 1, (cur + 1) & 1);
            __syncthreads();                 // staging visible (vmcnt drain)
        }
    };

    #pragma unroll 1
    for (int m2 = 1; m2 <= 29; m2 += 2) {
        STEP(m2,     sB, sA);
        STEP(m2 + 1, sA, sB);
    }
    STEP(31, sB, sA);                        // scores(31), softmax+PV(30)
    // ---- epilogue: softmax + PV of tile31 (in sXT[1]) ----
    {
        f16x8 pf0, pf1;
        SOFTMAX(sB, pf0, pf1);
        PV(1, pf0, pf1);
    }

    // --- normalize ---
    float inv = 1.0f / run_l;
    #pragma unroll
    for (int ob = 0; ob < 6; ++ob)
        #pragma unroll
        for (int i = 0; i < 16; ++i) vt[ob][i] *= inv;

    // --- combine: Y^T[dout][n] = sum_din WT[dout][din] * Vt^T[din][n] ---
    const u16* wbase = wtp_g + (size_t)th*36864;
    f32x16 y[6];
    #pragma unroll
    for (int ob = 0; ob < 6; ++ob)
        #pragma unroll
        for (int i = 0; i < 16; ++i) y[ob][i] = 0.0f;

    #pragma unroll
    for (int ob = 0; ob < 6; ++ob) {
        u32 qq[8];
        #pragma unroll
        for (int j = 0; j < 8; ++j) qq[j] = pk2h_rtz(vt[ob][2*j], vt[ob][2*j+1]);
        #pragma unroll
        for (int half = 0; half < 2; ++half) {
            int ks = ob*2 + half;
            f16x8 bfr = half ? make_bfrag(qq[4], qq[5], qq[6], qq[7], g32)
                             : make_bfrag(qq[0], qq[1], qq[2], qq[3], g32);
            #pragma unroll
            for (int ob2 = 0; ob2 < 6; ++ob2) {
                f16x8 a = *reinterpret_cast<const f16x8*>(
                    wbase + ((((size_t)ob2*12) + ks)*64 + lane)*8);
                y[ob2] = __builtin_amdgcn_mfma_f32_32x32x16_f16(a, bfr, y[ob2], 0, 0, 0);
            }
        }
    }

    // --- write partial Y[t][h][n][dout] (fp16) ---
    u16* yrow = y_g + ((size_t)th*1024 + n0 + l31)*D;
    #pragma unroll
    for (int ob = 0; ob < 6; ++ob)
        #pragma unroll
        for (int rq = 0; rq < 4; ++rq) {
            uint2 v;
            v.x = pk2h_rtz(y[ob][rq*4+0], y[ob][rq*4+1]);
            v.y = pk2h_rtz(y[ob][rq*4+2], y[ob][rq*4+3]);
            *reinterpret_cast<uint2*>(yrow + ob*32 + rq*8 + g32*4) = v;
        }
}

// =====================================================================
// Reduce: out[p*1024+n][d] = sum_{t in pair, h} y[t][h][n][d]  (fp16 in)
// =====================================================================
__global__ __launch_bounds__(512)
void reduce_y(const u16* __restrict__ y_g, float* __restrict__ out)
{
    int gi = blockIdx.x*512 + threadIdx.x;     // < 2048*192/8
    int n = gi / 24, c = gi - n*24;
    int p = n >> 10, nn = n & 1023;
    float acc[8];
    #pragma unroll
    for (int j = 0; j < 8; ++j) acc[j] = 0.0f;
    #pragma unroll
    for (int k = 0; k < 32; ++k) {
        int tcur = p*2 + (k >> 4), hh = k & 15;
        uint4 v = *reinterpret_cast<const uint4*>(
            y_g + ((size_t)((tcur*16+hh)*1024 + nn))*D + c*8);
        u32 w[4] = {v.x, v.y, v.z, v.w};
        #pragma unroll
        for (int j = 0; j < 4; ++j) {
            acc[2*j]   += h2f((u16)(w[j] & 0xffffu));
            acc[2*j+1] += h2f((u16)(w[j] >> 16));
        }
    }
    float* op = out + (size_t)n*D + c*8;
    float4 o0 = {acc[0], acc[1], acc[2], acc[3]};
    float4 o1 = {acc[4], acc[5], acc[6], acc[7]};
    *reinterpret_cast<float4*>(op)     = o0;
    *reinterpret_cast<float4*>(op + 4) = o1;
}

// =====================================================================
// Fallback (round-1 fp32 kernel) if ws too small
// =====================================================================
__global__ __launch_bounds__(256, 2)
void attn_fused_fb(const float* __restrict__ x,
                const float* __restrict__ Muu, const float* __restrict__ Mdd,
                const float* __restrict__ Mud, const float* __restrict__ Mdu,
                const float* __restrict__ Auu, const float* __restrict__ Add,
                const float* __restrict__ Aud, const float* __restrict__ Adu,
                float* __restrict__ out)
{
    const int nt  = blockIdx.x;
    const int h   = blockIdx.y;
    const int t   = blockIdx.z;
    const int tid = threadIdx.x;
    const float* qb = (t <= 1) ? x : x + (size_t)NUP*D;
    const float* kb = (t == 0 || t == 3) ? x : x + (size_t)NUP*D;
    const float* Mp = (t==0)?Muu:(t==1)?Mud:(t==2)?Mdd:Mdu;
    const float* Ap = (t==0)?Auu:(t==1)?Aud:(t==2)?Add:Adu;
    const float* Mh = Mp + (size_t)h*32*D;
    const float* Ah = Ap + (size_t)h*32*D;
    float* ob = out + ((t>=2) ? (size_t)NUP*D : 0);

    __shared__ float sK[32*196];
    __shared__ float sQM[32*196];
    __shared__ float sS[32*33];
    __shared__ float sTmp[32*8];
    __shared__ float sR[32];
    __shared__ float sMaxRun[32];
    __shared__ float sSumRun[32];

    if (tid < 32) { sMaxRun[tid] = -3.0e38f; sSumRun[tid] = 0.0f; }
    for (int i = tid; i < 32*D/4; i += 256)
        reinterpret_cast<float4*>(sK)[i] = reinterpret_cast<const float4*>(Mh)[i];
    __syncthreads();

    #pragma unroll
    for (int kk = 0; kk < 4; ++kk) {
        int p = tid + kk*256;
        int n = p >> 5, g = p & 31;
        const float* qrow = qb + (size_t)(nt*32 + n)*D;
        float acc[6] = {0,0,0,0,0,0};
        for (int f = 0; f < 32; ++f) {
            const float* qf = qrow + f*6;
            const float* mf = sK + f*D + g*6;
            #pragma unroll
            for (int z = 0; z < 3; ++z) {
                float q0 = qf[2*z], q1 = qf[2*z+1];
                float m0 = mf[2*z], m1 = mf[2*z+1];
                acc[2*z]   += q0*m0 - q1*m1;
                acc[2*z+1] += q1*m0 + q0*m1;
            }
        }
        #pragma unroll
        for (int j = 0; j < 6; ++j) sQM[n*196 + g*6 + j] = acc[j];
    }

    const int gn = tid >> 5;
    const int cg = tid & 31;
    const int cbase = cg*6;
    float vacc[4][6];
    #pragma unroll
    for (int a = 0; a < 4; ++a)
        #pragma unroll
        for (int b = 0; b < 6; ++b) vacc[a][b] = 0.0f;

    const int txm = tid & 15, tyn = tid >> 4;

    for (int mt = 0; mt < 32; ++mt) {
        __syncthreads();
        for (int i = tid; i < 32*(D/4); i += 256) {
            int row = i / (D/4), j = i - row*(D/4);
            float4 v = reinterpret_cast<const float4*>(kb + (size_t)(mt*32 + row)*D)[j];
            *reinterpret_cast<float4*>(&sK[row*196 + j*4]) = v;
        }
        __syncthreads();

        float a00=0,a01=0,a10=0,a11=0;
        {
            const float* q0p = &sQM[tyn*196];
            const float* q1p = &sQM[(tyn+16)*196];
            const float* k0p = &sK[txm*196];
            const float* k1p = &sK[(txm+16)*196];
            for (int k = 0; k < D; k += 4) {
                float4 qa = *reinterpret_cast<const float4*>(q0p+k);
                float4 qc = *reinterpret_cast<const float4*>(q1p+k);
                float4 ka = *reinterpret_cast<const float4*>(k0p+k);
                float4 kc = *reinterpret_cast<const float4*>(k1p+k);
                a00 += qa.x*ka.x + qa.y*ka.y + qa.z*ka.z + qa.w*ka.w;
                a01 += qa.x*kc.x + qa.y*kc.y + qa.z*kc.z + qa.w*kc.w;
                a10 += qc.x*ka.x + qc.y*ka.y + qc.z*ka.z + qc.w*ka.w;
                a11 += qc.x*kc.x + qc.y*kc.y + qc.z*kc.z + qc.w*kc.w;
            }
        }
        sS[tyn*33 + txm]          = a00;
        sS[tyn*33 + txm+16]       = a01;
        sS[(tyn+16)*33 + txm]     = a10;
        sS[(tyn+16)*33 + txm+16]  = a11;
        __syncthreads();

        const int srow = tid >> 3, sj = tid & 7;
        {
            const float* r = &sS[srow*33];
            float mx = fmaxf(fmaxf(r[sj], r[sj+8]), fmaxf(r[sj+16], r[sj+24]));
            sTmp[srow*8 + sj] = mx;
        }
        __syncthreads();
        if (tid < 32) {
            float mx = sTmp[tid*8];
            #pragma unroll
            for (int j = 1; j < 8; ++j) mx = fmaxf(mx, sTmp[tid*8+j]);
            float om = sMaxRun[tid];
            float nm = fmaxf(om, mx);
            sR[tid] = __expf(om - nm);
            sMaxRun[tid] = nm;
        }
        __syncthreads();
        {
            float nm = sMaxRun[srow];
            float* r = &sS[srow*33];
            float p0 = __expf(r[sj]    - nm);
            float p1 = __expf(r[sj+8]  - nm);
            float p2 = __expf(r[sj+16] - nm);
            float p3 = __expf(r[sj+24] - nm);
            r[sj] = p0; r[sj+8] = p1; r[sj+16] = p2; r[sj+24] = p3;
            sTmp[srow*8+sj] = p0+p1+p2+p3;
        }
        __syncthreads();
        if (tid < 32) {
            float s = 0.0f;
            #pragma unroll
            for (int j = 0; j < 8; ++j) s += sTmp[tid*8+j];
            sSumRun[tid] = sSumRun[tid]*sR[tid] + s;
        }
        {
            float r0 = sR[gn*4+0], r1 = sR[gn*4+1], r2 = sR[gn*4+2], r3 = sR[gn*4+3];
            #pragma unroll
            for (int b = 0; b < 6; ++b) { vacc[0][b]*=r0; vacc[1][b]*=r1; vacc[2][b]*=r2; vacc[3][b]*=r3; }
            for (int m = 0; m < 32; ++m) {
                float p0 = sS[(gn*4+0)*33+m];
                float p1 = sS[(gn*4+1)*33+m];
                float p2 = sS[(gn*4+2)*33+m];
                float p3 = sS[(gn*4+3)*33+m];
                const float* kr = &sK[m*196 + cbase];
                #pragma unroll
                for (int b = 0; b < 6; ++b) {
                    float kv = kr[b];
                    vacc[0][b] += p0*kv;
                    vacc[1][b] += p1*kv;
                    vacc[2][b] += p2*kv;
                    vacc[3][b] += p3*kv;
                }
            }
        }
    }

    __syncthreads();
    {
        float i0 = 1.0f/sSumRun[gn*4+0], i1 = 1.0f/sSumRun[gn*4+1];
        float i2 = 1.0f/sSumRun[gn*4+2], i3 = 1.0f/sSumRun[gn*4+3];
        #pragma unroll
        for (int b = 0; b < 6; ++b) {
            sQM[(gn*4+0)*196 + cbase + b] = vacc[0][b]*i0;
            sQM[(gn*4+1)*196 + cbase + b] = vacc[1][b]*i1;
            sQM[(gn*4+2)*196 + cbase + b] = vacc[2][b]*i2;
            sQM[(gn*4+3)*196 + cbase + b] = vacc[3][b]*i3;
        }
    }
    for (int i = tid; i < 32*D/4; i += 256)
        reinterpret_cast<float4*>(sK)[i] = reinterpret_cast<const float4*>(Ah)[i];
    __syncthreads();

    #pragma unroll
    for (int kk = 0; kk < 4; ++kk) {
        int p = tid + kk*256;
        int n = p >> 5, g = p & 31;
        float acc[6] = {0,0,0,0,0,0};
        const float* vb = &sQM[n*196];
        const float* ab = &sK[g*D];
        for (int f = 0; f < 32; ++f) {
            const float* vf = vb + f*6;
            const float* af = ab + f*6;
            #pragma unroll
            for (int z = 0; z < 3; ++z) {
                float V0 = vf[2*z], V1 = vf[2*z+1];
                float A0 = af[2*z], A1 = af[2*z+1];
                acc[2*z]   += A0*V0 - A1*V1;
                acc[2*z+1] += A0*V1 + A1*V0;
            }
        }
        float* op = ob + (size_t)(nt*32 + n)*D + g*6;
        #pragma unroll
        for (int j = 0; j < 6; ++j) atomicAdd(op + j, acc[j]);
    }
}

extern "C" void kernel_launch(void* const* d_in, const int* in_sizes, int n_in,
                              void* d_out, int out_size, void* d_ws, size_t ws_size,
                              hipStream_t stream) {
    const float* x   = (const float*)d_in[0];
    const float* Muu = (const float*)d_in[1];
    const float* Mdd = (const float*)d_in[2];
    const float* Mud = (const float*)d_in[3];
    const float* Mdu = (const float*)d_in[4];
    const float* Auu = (const float*)d_in[5];
    const float* Add = (const float*)d_in[6];
    const float* Aud = (const float*)d_in[7];
    const float* Adu = (const float*)d_in[8];
    float* outp = (float*)d_out;

    if (ws_size >= WS_NEED) {
        char* ws = (char*)d_ws;
        u16* xh  = (u16*)(ws + XH_OFF);
        u16* xl  = (u16*)(ws + XL_OFF);
        u16* xT  = (u16*)(ws + XT_OFF);
        u16* wtp = (u16*)(ws + WTP_OFF);
        u16* mth = (u16*)(ws + MTH_OFF);
        u16* mtl = (u16*)(ws + MTL_OFF);
        u16* y   = (u16*)(ws + Y_OFF);

        prep_all<<<5376, 512, 0, stream>>>(x, Muu, Mdd, Mud, Mdu,
                                           Auu, Add, Aud, Adu,
                                           xh, xl, xT, wtp, mth, mtl);
        attn_mfma<<<dim3(8, 16, 4), 256, 0, stream>>>(xh, xl, xT, wtp, mth, mtl, y);
        reduce_y<<<96, 512, 0, stream>>>(y, outp);
    } else {
        (void)hipMemsetAsync(d_out, 0, (size_t)out_size * sizeof(float), stream);
        attn_fused_fb<<<dim3(32, 16, 4), 256, 0, stream>>>(x, Muu, Mdd, Mud, Mdu,
                                                           Auu, Add, Aud, Adu, outp);
    }
}

// Round 17
// 127.967 us; speedup vs baseline: 1.3351x; 1.0180x over previous
//
#include <hip/hip_runtime.h>
#include <hip/hip_bf16.h>

typedef unsigned short u16;
typedef unsigned int   u32;
typedef _Float16 f16x8 __attribute__((ext_vector_type(8)));
typedef float    f32x16 __attribute__((ext_vector_type(16)));

#define HEADS 16
#define D     192
#define NUP   1024

// ---- workspace layout (bytes) ----
#define XB       (2048ull*192*2)               // 786432
#define XH_OFF   0ull
#define XL_OFF   (XH_OFF + XB)
#define XT_OFF   (XL_OFF + XB)
#define WM_BYTES (64ull*192*192*2)             // 4718592
#define WTP_OFF  (XT_OFF + XB)
#define MTH_OFF  (WTP_OFF + WM_BYTES)
#define MTL_OFF  (MTH_OFF + WM_BYTES)
#define Y_BYTES  (64ull*1024*192*2)            // 25165824 (fp16)
#define Y_OFF    (MTH_OFF + 2*WM_BYTES)
#define WS_NEED  (Y_OFF + Y_BYTES)             // 41680896

__device__ __forceinline__ u16 f2h(float v) {
    _Float16 h = (_Float16)v;
    return __builtin_bit_cast(u16, h);
}
__device__ __forceinline__ float h2f(u16 v) {
    return (float)__builtin_bit_cast(_Float16, v);
}
__device__ __forceinline__ u32 pk2h(float a, float b) {      // RNE
    return (u32)f2h(a) | ((u32)f2h(b) << 16);
}
__device__ __forceinline__ u32 pk2h_rtz(float a, float b) {  // 1-instr packed
    auto r = __builtin_amdgcn_cvt_pkrtz(a, b);
    return __builtin_bit_cast(u32, r);
}

// =====================================================================
// helper: assemble B-fragment (32x32x16) from 4 packed-pair u32s in
// D-frag order (m = (r&3)+8*(r>>2)+4*(lane>>5)) via half-swap (shfl —
// HW-verified R2..R12)
// =====================================================================
__device__ __forceinline__ f16x8 make_bfrag(u32 q0, u32 q1, u32 q2, u32 q3, bool hi) {
    u32 s0 = (u32)__shfl_xor((int)q0, 32);
    u32 s1 = (u32)__shfl_xor((int)q1, 32);
    u32 s2 = (u32)__shfl_xor((int)q2, 32);
    u32 s3 = (u32)__shfl_xor((int)q3, 32);
    uint4 w;
    w.x = hi ? s2 : q0;  w.y = hi ? s3 : q1;
    w.z = hi ? q2 : s0;  w.w = hi ? q3 : s1;
    return __builtin_bit_cast(f16x8, w);
}

// =====================================================================
// Prep ALL (merged): blocks [0,768) do x->xh,xl,xT ; rest build WT/MT.
// =====================================================================
__global__ __launch_bounds__(512)
void prep_all(const float* __restrict__ x,
              const float* __restrict__ Muu, const float* __restrict__ Mdd,
              const float* __restrict__ Mud, const float* __restrict__ Mdu,
              const float* __restrict__ Auu, const float* __restrict__ Add,
              const float* __restrict__ Aud, const float* __restrict__ Adu,
              u16* __restrict__ xh, u16* __restrict__ xl, u16* __restrict__ xT,
              u16* __restrict__ wtp, u16* __restrict__ mth, u16* __restrict__ mtl)
{
    int b = blockIdx.x;
    if (b < 768) {
        int i = b*512 + threadIdx.x;           // < 2048*192
        float v = x[i];
        int n = i / D, d = i - n*D;
        u16 hi = f2h(v);
        xh[i] = hi;
        xl[i] = f2h(v - h2f(hi));
        xT[(size_t)(n >> 5)*6144 + d*32 + (n & 31)] = hi;
        return;
    }
    int idx = (b - 768)*512 + threadIdx.x;     // < 64*36864
    int th = idx / 36864, r = idx - th*36864;
    int dout = r / 192, din = r - dout*192;
    int t = th >> 4, h = th & 15;
    const float* Ap = (t==0)?Auu:(t==1)?Aud:(t==2)?Add:Adu;
    const float* Mp = (t==0)?Muu:(t==1)?Mud:(t==2)?Mdd:Mdu;
    int g = dout / 6, zc = dout - g*6, z = zc >> 1, b0 = zc & 1;
    int f = din / 6,  zb = din - f*6,  z2 = zb >> 1, b1 = zb & 1;

    float wv = 0.0f, mv = 0.0f;
    if (z2 == z) {
        const float* a = Ap + (((size_t)h*32 + g)*32 + f)*6 + z*2;
        float A0 = a[0], A1 = a[1];
        wv = (b0 == 0) ? (b1 == 0 ? A0 : -A1) : (b1 == 0 ? A1 : A0);
        const float* m = Mp + (((size_t)h*32 + f)*32 + g)*6 + z*2;
        float M0 = m[0], M1 = m[1];
        mv = (b0 == 0) ? (b1 == 0 ? M0 : -M1) : (b1 == 0 ? M1 : M0);
    }
    int ob = dout >> 5, l31 = dout & 31;
    int ks = din >> 4, kr = din & 15, g32 = kr >> 3, j = kr & 7;
    size_t pidx = ((((size_t)th*6 + ob)*12 + ks)*64 + g32*32 + l31)*8 + j;
    wtp[pidx] = f2h(wv);
    u16 mh = f2h(mv);
    mth[pidx] = mh;
    mtl[pidx] = f2h(mv - h2f(mh));
}

// =====================================================================
// Main fused kernel — 8 waves x 32 q-rows, 512 threads, grid (4,16,4).
// Prologue: QM B-fragments via MFMA (3-term, 2-ob pairs). K-loop:
// 1-term fp16 scores (2x6-chain split) + PV, T15 lag-softmax,
// triple-buffer LDS, one barrier/iter.  [R12 configuration — best]
// =====================================================================
__global__ __launch_bounds__(512, 2)
void attn_mfma(const u16* __restrict__ xh_g,  const u16* __restrict__ xl_g,
               const u16* __restrict__ xT_g,  const u16* __restrict__ wtp_g,
               const u16* __restrict__ mth_g, const u16* __restrict__ mtl_g,
               u16* __restrict__ y_g)
{
    const int nt = blockIdx.x, h = blockIdx.y, t = blockIdx.z;
    const int tid  = threadIdx.x;
    const int lane = tid & 63;
    const int l31  = lane & 31;
    const int g32  = lane >> 5;
    const int th   = t*16 + h;
    const int n0   = nt*256 + (tid >> 6)*32;
    const int qoff = (t <= 1) ? 0 : NUP;             // q-side rows
    const int koff = (t == 1 || t == 2) ? NUP : 0;   // k/v-side rows
    const int mtb  = koff >> 5;

    __shared__ u16 sXh[3][32*200];
    __shared__ u16 sXT[3][192*40];

    // ---- prologue: QM B-fragments via MFMA (3-term fp16 split) ----
    f16x8 qh[12];
    {
        f16x8 bxh[12], bxl[12];
        const u16* xrh = xh_g + (size_t)(qoff + n0 + l31)*D;
        const u16* xrl = xl_g + (size_t)(qoff + n0 + l31)*D;
        #pragma unroll
        for (int ks = 0; ks < 12; ++ks) {
            bxh[ks] = *reinterpret_cast<const f16x8*>(xrh + ks*16 + g32*8);
            bxl[ks] = *reinterpret_cast<const f16x8*>(xrl + ks*16 + g32*8);
        }
        const u16* mthb = mth_g + (size_t)th*36864;
        const u16* mtlb = mtl_g + (size_t)th*36864;
        #pragma unroll
        for (int obp = 0; obp < 3; ++obp) {      // 2 obs in flight for ILP
            const int ob0 = obp*2, ob1 = obp*2 + 1;
            f32x16 a0, a1;
            #pragma unroll
            for (int i = 0; i < 16; ++i) { a0[i] = 0.0f; a1[i] = 0.0f; }
            #pragma unroll
            for (int ks = 0; ks < 12; ++ks) {
                size_t fo0 = (((size_t)ob0*12 + ks)*64 + lane)*8;
                size_t fo1 = (((size_t)ob1*12 + ks)*64 + lane)*8;
                f16x8 amh0 = *reinterpret_cast<const f16x8*>(mthb + fo0);
                f16x8 aml0 = *reinterpret_cast<const f16x8*>(mtlb + fo0);
                f16x8 amh1 = *reinterpret_cast<const f16x8*>(mthb + fo1);
                f16x8 aml1 = *reinterpret_cast<const f16x8*>(mtlb + fo1);
                a0 = __builtin_amdgcn_mfma_f32_32x32x16_f16(amh0, bxh[ks], a0, 0, 0, 0);
                a1 = __builtin_amdgcn_mfma_f32_32x32x16_f16(amh1, bxh[ks], a1, 0, 0, 0);
                a0 = __builtin_amdgcn_mfma_f32_32x32x16_f16(amh0, bxl[ks], a0, 0, 0, 0);
                a1 = __builtin_amdgcn_mfma_f32_32x32x16_f16(amh1, bxl[ks], a1, 0, 0, 0);
                a0 = __builtin_amdgcn_mfma_f32_32x32x16_f16(aml0, bxh[ks], a0, 0, 0, 0);
                a1 = __builtin_amdgcn_mfma_f32_32x32x16_f16(aml1, bxh[ks], a1, 0, 0, 0);
            }
            u32 h0[8], h1[8];
            #pragma unroll
            for (int j = 0; j < 8; ++j) {
                h0[j] = pk2h(a0[2*j], a0[2*j+1]);
                h1[j] = pk2h(a1[2*j], a1[2*j+1]);
            }
            qh[ob0*2+0] = make_bfrag(h0[0], h0[1], h0[2], h0[3], g32);
            qh[ob0*2+1] = make_bfrag(h0[4], h0[5], h0[6], h0[7], g32);
            qh[ob1*2+0] = make_bfrag(h1[0], h1[1], h1[2], h1[3], g32);
            qh[ob1*2+1] = make_bfrag(h1[4], h1[5], h1[6], h1[7], g32);
        }
    }

    f32x16 vt[6];
    #pragma unroll
    for (int ob = 0; ob < 6; ++ob)
        #pragma unroll
        for (int i = 0; i < 16; ++i) vt[ob][i] = 0.0f;

    float run_m = -3.0e38f, run_l = 0.0f;

    uint4 ld[3];
    auto load_tile = [&](int mt) {
        const int krow0 = koff + mt*32;
        #pragma unroll
        for (int i = 0; i < 3; ++i) {
            int c = tid + i*512;
            const u16* gp;
            if (c < 768) {
                int rr = c/24, cc = c - rr*24;
                gp = xh_g + (size_t)(krow0 + rr)*D + cc*8;
            } else {
                int c3 = c - 768, dd = c3 >> 2, qq = c3 & 3;
                gp = xT_g + (size_t)(mtb + mt)*6144 + dd*32 + qq*8;
            }
            ld[i] = *reinterpret_cast<const uint4*>(gp);
        }
    };
    auto store_tile = [&](int buf) {
        #pragma unroll
        for (int i = 0; i < 3; ++i) {
            int c = tid + i*512;
            u16* lp;
            if (c < 768) {
                int rr = c/24, cc = c - rr*24;  lp = &sXh[buf][rr*200 + cc*8];
            } else {
                int c3 = c - 768, dd = c3 >> 2, qq = c3 & 3;  lp = &sXT[buf][dd*40 + qq*8];
            }
            *reinterpret_cast<uint4*>(lp) = ld[i];
        }
    };
    auto SCORES = [&](int bc, f32x16 &sOut) {
        f32x16 s0, s1;
        #pragma unroll
        for (int i = 0; i < 16; ++i) { s0[i] = 0.0f; s1[i] = 0.0f; }
        __builtin_amdgcn_s_setprio(1);
        #pragma unroll
        for (int ks = 0; ks < 6; ++ks) {
            f16x8 ah0 = *reinterpret_cast<const f16x8*>(&sXh[bc][l31*200 + ks*16 + g32*8]);
            f16x8 ah1 = *reinterpret_cast<const f16x8*>(&sXh[bc][l31*200 + (ks+6)*16 + g32*8]);
            s0 = __builtin_amdgcn_mfma_f32_32x32x16_f16(ah0, qh[ks],   s0, 0, 0, 0);
            s1 = __builtin_amdgcn_mfma_f32_32x32x16_f16(ah1, qh[ks+6], s1, 0, 0, 0);
        }
        __builtin_amdgcn_s_setprio(0);
        #pragma unroll
        for (int i = 0; i < 16; ++i) sOut[i] = s0[i] + s1[i];
    };
    auto SOFTMAX = [&](f32x16 &sIn, f16x8 &pf0, f16x8 &pf1) {
        float tmax = sIn[0];
        #pragma unroll
        for (int i = 1; i < 16; ++i) tmax = fmaxf(tmax, sIn[i]);
        tmax = fmaxf(tmax, __shfl_xor(tmax, 32));
        if (__any(tmax > run_m + 8.0f)) {       // defer-rescale (T13)
            float nm = fmaxf(run_m, tmax);
            float rs = __expf(run_m - nm);
            #pragma unroll
            for (int ob = 0; ob < 6; ++ob)
                #pragma unroll
                for (int i = 0; i < 16; ++i) vt[ob][i] *= rs;
            run_l *= rs;
            run_m = nm;
        }
        float psum = 0.0f;
        u32 q[8];
        #pragma unroll
        for (int j = 0; j < 8; ++j) {
            float p0 = __expf(sIn[2*j]   - run_m);
            float p1 = __expf(sIn[2*j+1] - run_m);
            psum += p0 + p1;
            q[j] = pk2h_rtz(p0, p1);
        }
        psum += __shfl_xor(psum, 32);
        run_l += psum;
        pf0 = make_bfrag(q[0], q[1], q[2], q[3], g32);
        pf1 = make_bfrag(q[4], q[5], q[6], q[7], g32);
    };
    auto PV = [&](int bp, f16x8 pf0, f16x8 pf1) {
        __builtin_amdgcn_s_setprio(1);
        #pragma unroll
        for (int ob = 0; ob < 6; ++ob) {
            f16x8 a0 = *reinterpret_cast<const f16x8*>(&sXT[bp][(ob*32 + l31)*40 + g32*8]);
            f16x8 a1 = *reinterpret_cast<const f16x8*>(&sXT[bp][(ob*32 + l31)*40 + 16 + g32*8]);
            vt[ob] = __builtin_amdgcn_mfma_f32_32x32x16_f16(a0, pf0, vt[ob], 0, 0, 0);
            vt[ob] = __builtin_amdgcn_mfma_f32_32x32x16_f16(a1, pf1, vt[ob], 0, 0, 0);
        }
        __builtin_amdgcn_s_setprio(0);
    };

    f32x16 sA, sB;

    // ---- pipeline prologue: tile0 staged+scored; tile1 staged ----
    load_tile(0); store_tile(0); __syncthreads();
    load_tile(1);
    SCORES(0, sA);
    store_tile(1); __syncthreads();

    auto STEP = [&](int cur, f32x16 &sCur, f32x16 &sPrev, int bC, int bP, int bN) {
        if (cur < 31) load_tile(cur + 1);
        SCORES(bC, sCur);                    // MFMA(cur) issues...
        f16x8 pf0, pf1;
        SOFTMAX(sPrev, pf0, pf1);            // ...while VALU does softmax(prev)
        PV(bP, pf0, pf1);
        if (cur < 31) store_tile(bN);
        __syncthreads();
    };

    // buffers at cur=1: cur%3=1, prev=0, next=2; rotate each step
    int b0 = 1, b1 = 0, b2 = 2;
    #pragma unroll 1
    for (int m2 = 1; m2 <= 29; m2 += 2) {
        STEP(m2,     sB, sA, b0, b1, b2);
        { int tq = b1; b1 = b0; b0 = b2; b2 = tq; }
        STEP(m2 + 1, sA, sB, b0, b1, b2);
        { int tq = b1; b1 = b0; b0 = b2; b2 = tq; }
    }
    STEP(31, sB, sA, b0, b1, b2);            // scores(31), softmax+PV(30)
    // ---- epilogue: softmax + PV of tile31 (lives in buffer b0) ----
    {
        f16x8 pf0, pf1;
        SOFTMAX(sB, pf0, pf1);
        PV(b0, pf0, pf1);
    }

    // --- normalize ---
    float inv = 1.0f / run_l;
    #pragma unroll
    for (int ob = 0; ob < 6; ++ob)
        #pragma unroll
        for (int i = 0; i < 16; ++i) vt[ob][i] *= inv;

    // --- combine: Y^T[dout][n] = sum_din WT[dout][din] * Vt^T[din][n] ---
    const u16* wbase = wtp_g + (size_t)th*36864;
    f32x16 y[6];
    #pragma unroll
    for (int ob = 0; ob < 6; ++ob)
        #pragma unroll
        for (int i = 0; i < 16; ++i) y[ob][i] = 0.0f;

    #pragma unroll
    for (int ob = 0; ob < 6; ++ob) {
        u32 qq[8];
        #pragma unroll
        for (int j = 0; j < 8; ++j) qq[j] = pk2h_rtz(vt[ob][2*j], vt[ob][2*j+1]);
        #pragma unroll
        for (int half = 0; half < 2; ++half) {
            int ks = ob*2 + half;
            f16x8 bfr = half ? make_bfrag(qq[4], qq[5], qq[6], qq[7], g32)
                             : make_bfrag(qq[0], qq[1], qq[2], qq[3], g32);
            #pragma unroll
            for (int ob2 = 0; ob2 < 6; ++ob2) {
                f16x8 a = *reinterpret_cast<const f16x8*>(
                    wbase + ((((size_t)ob2*12) + ks)*64 + lane)*8);
                y[ob2] = __builtin_amdgcn_mfma_f32_32x32x16_f16(a, bfr, y[ob2], 0, 0, 0);
            }
        }
    }

    // --- write partial Y[t][h][n][dout] (fp16) ---
    u16* yrow = y_g + ((size_t)th*1024 + n0 + l31)*D;
    #pragma unroll
    for (int ob = 0; ob < 6; ++ob)
        #pragma unroll
        for (int rq = 0; rq < 4; ++rq) {
            uint2 v;
            v.x = pk2h_rtz(y[ob][rq*4+0], y[ob][rq*4+1]);
            v.y = pk2h_rtz(y[ob][rq*4+2], y[ob][rq*4+3]);
            *reinterpret_cast<uint2*>(yrow + ob*32 + rq*8 + g32*4) = v;
        }
}

// =====================================================================
// Reduce: out[p*1024+n][d] = sum_{t in pair, h} y[t][h][n][d]  (fp16 in)
// =====================================================================
__global__ __launch_bounds__(512)
void reduce_y(const u16* __restrict__ y_g, float* __restrict__ out)
{
    int gi = blockIdx.x*512 + threadIdx.x;     // < 2048*192/8
    int n = gi / 24, c = gi - n*24;
    int p = n >> 10, nn = n & 1023;
    float acc[8];
    #pragma unroll
    for (int j = 0; j < 8; ++j) acc[j] = 0.0f;
    #pragma unroll
    for (int k = 0; k < 32; ++k) {
        int tcur = p*2 + (k >> 4), hh = k & 15;
        uint4 v = *reinterpret_cast<const uint4*>(
            y_g + ((size_t)((tcur*16+hh)*1024 + nn))*D + c*8);
        u32 w[4] = {v.x, v.y, v.z, v.w};
        #pragma unroll
        for (int j = 0; j < 4; ++j) {
            acc[2*j]   += h2f((u16)(w[j] & 0xffffu));
            acc[2*j+1] += h2f((u16)(w[j] >> 16));
        }
    }
    float* op = out + (size_t)n*D + c*8;
    float4 o0 = {acc[0], acc[1], acc[2], acc[3]};
    float4 o1 = {acc[4], acc[5], acc[6], acc[7]};
    *reinterpret_cast<float4*>(op)     = o0;
    *reinterpret_cast<float4*>(op + 4) = o1;
}

// =====================================================================
// Fallback (round-1 fp32 kernel) if ws too small
// =====================================================================
__global__ __launch_bounds__(256, 2)
void attn_fused_fb(const float* __restrict__ x,
                const float* __restrict__ Muu, const float* __restrict__ Mdd,
                const float* __restrict__ Mud, const float* __restrict__ Mdu,
                const float* __restrict__ Auu, const float* __restrict__ Add,
                const float* __restrict__ Aud, const float* __restrict__ Adu,
                float* __restrict__ out)
{
    const int nt  = blockIdx.x;
    const int h   = blockIdx.y;
    const int t   = blockIdx.z;
    const int tid = threadIdx.x;
    const float* qb = (t <= 1) ? x : x + (size_t)NUP*D;
    const float* kb = (t == 0 || t == 3) ? x : x + (size_t)NUP*D;
    const float* Mp = (t==0)?Muu:(t==1)?Mud:(t==2)?Mdd:Mdu;
    const float* Ap = (t==0)?Auu:(t==1)?Aud:(t==2)?Add:Adu;
    const float* Mh = Mp + (size_t)h*32*D;
    const float* Ah = Ap + (size_t)h*32*D;
    float* ob = out + ((t>=2) ? (size_t)NUP*D : 0);

    __shared__ float sK[32*196];
    __shared__ float sQM[32*196];
    __shared__ float sS[32*33];
    __shared__ float sTmp[32*8];
    __shared__ float sR[32];
    __shared__ float sMaxRun[32];
    __shared__ float sSumRun[32];

    if (tid < 32) { sMaxRun[tid] = -3.0e38f; sSumRun[tid] = 0.0f; }
    for (int i = tid; i < 32*D/4; i += 256)
        reinterpret_cast<float4*>(sK)[i] = reinterpret_cast<const float4*>(Mh)[i];
    __syncthreads();

    #pragma unroll
    for (int kk = 0; kk < 4; ++kk) {
        int p = tid + kk*256;
        int n = p >> 5, g = p & 31;
        const float* qrow = qb + (size_t)(nt*32 + n)*D;
        float acc[6] = {0,0,0,0,0,0};
        for (int f = 0; f < 32; ++f) {
            const float* qf = qrow + f*6;
            const float* mf = sK + f*D + g*6;
            #pragma unroll
            for (int z = 0; z < 3; ++z) {
                float q0 = qf[2*z], q1 = qf[2*z+1];
                float m0 = mf[2*z], m1 = mf[2*z+1];
                acc[2*z]   += q0*m0 - q1*m1;
                acc[2*z+1] += q1*m0 + q0*m1;
            }
        }
        #pragma unroll
        for (int j = 0; j < 6; ++j) sQM[n*196 + g*6 + j] = acc[j];
    }

    const int gn = tid >> 5;
    const int cg = tid & 31;
    const int cbase = cg*6;
    float vacc[4][6];
    #pragma unroll
    for (int a = 0; a < 4; ++a)
        #pragma unroll
        for (int b = 0; b < 6; ++b) vacc[a][b] = 0.0f;

    const int txm = tid & 15, tyn = tid >> 4;

    for (int mt = 0; mt < 32; ++mt) {
        __syncthreads();
        for (int i = tid; i < 32*(D/4); i += 256) {
            int row = i / (D/4), j = i - row*(D/4);
            float4 v = reinterpret_cast<const float4*>(kb + (size_t)(mt*32 + row)*D)[j];
            *reinterpret_cast<float4*>(&sK[row*196 + j*4]) = v;
        }
        __syncthreads();

        float a00=0,a01=0,a10=0,a11=0;
        {
            const float* q0p = &sQM[tyn*196];
            const float* q1p = &sQM[(tyn+16)*196];
            const float* k0p = &sK[txm*196];
            const float* k1p = &sK[(txm+16)*196];
            for (int k = 0; k < D; k += 4) {
                float4 qa = *reinterpret_cast<const float4*>(q0p+k);
                float4 qc = *reinterpret_cast<const float4*>(q1p+k);
                float4 ka = *reinterpret_cast<const float4*>(k0p+k);
                float4 kc = *reinterpret_cast<const float4*>(k1p+k);
                a00 += qa.x*ka.x + qa.y*ka.y + qa.z*ka.z + qa.w*ka.w;
                a01 += qa.x*kc.x + qa.y*kc.y + qa.z*kc.z + qa.w*kc.w;
                a10 += qc.x*ka.x + qc.y*ka.y + qc.z*ka.z + qc.w*ka.w;
                a11 += qc.x*kc.x + qc.y*kc.y + qc.z*kc.z + qc.w*kc.w;
            }
        }
        sS[tyn*33 + txm]          = a00;
        sS[tyn*33 + txm+16]       = a01;
        sS[(tyn+16)*33 + txm]     = a10;
        sS[(tyn+16)*33 + txm+16]  = a11;
        __syncthreads();

        const int srow = tid >> 3, sj = tid & 7;
        {
            const float* r = &sS[srow*33];
            float mx = fmaxf(fmaxf(r[sj], r[sj+8]), fmaxf(r[sj+16], r[sj+24]));
            sTmp[srow*8 + sj] = mx;
        }
        __syncthreads();
        if (tid < 32) {
            float mx = sTmp[tid*8];
            #pragma unroll
            for (int j = 1; j < 8; ++j) mx = fmaxf(mx, sTmp[tid*8+j]);
            float om = sMaxRun[tid];
            float nm = fmaxf(om, mx);
            sR[tid] = __expf(om - nm);
            sMaxRun[tid] = nm;
        }
        __syncthreads();
        {
            float nm = sMaxRun[srow];
            float* r = &sS[srow*33];
            float p0 = __expf(r[sj]    - nm);
            float p1 = __expf(r[sj+8]  - nm);
            float p2 = __expf(r[sj+16] - nm);
            float p3 = __expf(r[sj+24] - nm);
            r[sj] = p0; r[sj+8] = p1; r[sj+16] = p2; r[sj+24] = p3;
            sTmp[srow*8+sj] = p0+p1+p2+p3;
        }
        __syncthreads();
        if (tid < 32) {
            float s = 0.0f;
            #pragma unroll
            for (int j = 0; j < 8; ++j) s += sTmp[tid*8+j];
            sSumRun[tid] = sSumRun[tid]*sR[tid] + s;
        }
        {
            float r0 = sR[gn*4+0], r1 = sR[gn*4+1], r2 = sR[gn*4+2], r3 = sR[gn*4+3];
            #pragma unroll
            for (int b = 0; b < 6; ++b) { vacc[0][b]*=r0; vacc[1][b]*=r1; vacc[2][b]*=r2; vacc[3][b]*=r3; }
            for (int m = 0; m < 32; ++m) {
                float p0 = sS[(gn*4+0)*33+m];
                float p1 = sS[(gn*4+1)*33+m];
                float p2 = sS[(gn*4+2)*33+m];
                float p3 = sS[(gn*4+3)*33+m];
                const float* kr = &sK[m*196 + cbase];
                #pragma unroll
                for (int b = 0; b < 6; ++b) {
                    float kv = kr[b];
                    vacc[0][b] += p0*kv;
                    vacc[1][b] += p1*kv;
                    vacc[2][b] += p2*kv;
                    vacc[3][b] += p3*kv;
                }
            }
        }
    }

    __syncthreads();
    {
        float i0 = 1.0f/sSumRun[gn*4+0], i1 = 1.0f/sSumRun[gn*4+1];
        float i2 = 1.0f/sSumRun[gn*4+2], i3 = 1.0f/sSumRun[gn*4+3];
        #pragma unroll
        for (int b = 0; b < 6; ++b) {
            sQM[(gn*4+0)*196 + cbase + b] = vacc[0][b]*i0;
            sQM[(gn*4+1)*196 + cbase + b] = vacc[1][b]*i1;
            sQM[(gn*4+2)*196 + cbase + b] = vacc[2][b]*i2;
            sQM[(gn*4+3)*196 + cbase + b] = vacc[3][b]*i3;
        }
    }
    for (int i = tid; i < 32*D/4; i += 256)
        reinterpret_cast<float4*>(sK)[i] = reinterpret_cast<const float4*>(Ah)[i];
    __syncthreads();

    #pragma unroll
    for (int kk = 0; kk < 4; ++kk) {
        int p = tid + kk*256;
        int n = p >> 5, g = p & 31;
        float acc[6] = {0,0,0,0,0,0};
        const float* vb = &sQM[n*196];
        const float* ab = &sK[g*D];
        for (int f = 0; f < 32; ++f) {
            const float* vf = vb + f*6;
            const float* af = ab + f*6;
            #pragma unroll
            for (int z = 0; z < 3; ++z) {
                float V0 = vf[2*z], V1 = vf[2*z+1];
                float A0 = af[2*z], A1 = af[2*z+1];
                acc[2*z]   += A0*V0 - A1*V1;
                acc[2*z+1] += A0*V1 + A1*V0;
            }
        }
        float* op = ob + (size_t)(nt*32 + n)*D + g*6;
        #pragma unroll
        for (int j = 0; j < 6; ++j) atomicAdd(op + j, acc[j]);
    }
}

extern "C" void kernel_launch(void* const* d_in, const int* in_sizes, int n_in,
                              void* d_out, int out_size, void* d_ws, size_t ws_size,
                              hipStream_t stream) {
    const float* x   = (const float*)d_in[0];
    const float* Muu = (const float*)d_in[1];
    const float* Mdd = (const float*)d_in[2];
    const float* Mud = (const float*)d_in[3];
    const float* Mdu = (const float*)d_in[4];
    const float* Auu = (const float*)d_in[5];
    const float* Add = (const float*)d_in[6];
    const float* Aud = (const float*)d_in[7];
    const float* Adu = (const float*)d_in[8];
    float* outp = (float*)d_out;

    if (ws_size >= WS_NEED) {
        char* ws = (char*)d_ws;
        u16* xh  = (u16*)(ws + XH_OFF);
        u16* xl  = (u16*)(ws + XL_OFF);
        u16* xT  = (u16*)(ws + XT_OFF);
        u16* wtp = (u16*)(ws + WTP_OFF);
        u16* mth = (u16*)(ws + MTH_OFF);
        u16* mtl = (u16*)(ws + MTL_OFF);
        u16* y   = (u16*)(ws + Y_OFF);

        prep_all<<<5376, 512, 0, stream>>>(x, Muu, Mdd, Mud, Mdu,
                                           Auu, Add, Aud, Adu,
                                           xh, xl, xT, wtp, mth, mtl);
        attn_mfma<<<dim3(4, 16, 4), 512, 0, stream>>>(xh, xl, xT, wtp, mth, mtl, y);
        reduce_y<<<96, 512, 0, stream>>>(y, outp);
    } else {
        (void)hipMemsetAsync(d_out, 0, (size_t)out_size * sizeof(float), stream);
        attn_fused_fb<<<dim3(32, 16, 4), 256, 0, stream>>>(x, Muu, Mdd, Mud, Mdu,
                                                           Auu, Add, Aud, Adu, outp);
    }
}